// Round 5
// baseline (320.158 us; speedup 1.0000x reference)
//
#include <hip/hip_runtime.h>
#include <hip/hip_bf16.h>
#include <math.h>

#define NL 4
#define DMODEL 256
#define NH 8
#define FFDIM 1024
#define BB 4
#define SS 1024
#define HDIM 32
#define MROWS (BB * SS)   // 4096
#define LN_EPS 1e-5f

typedef __bf16 bf16x8 __attribute__((ext_vector_type(8)));
typedef float f32x4 __attribute__((ext_vector_type(4)));
typedef unsigned int u32;

__device__ __forceinline__ ushort f2bf(float f) {
    uint u = __builtin_bit_cast(uint, f);
    u += 0x7fff + ((u >> 16) & 1);          // round-to-nearest-even
    return (ushort)(u >> 16);
}
__device__ __forceinline__ uint pack2(float a, float b) {
    return (uint)f2bf(a) | ((uint)f2bf(b) << 16);
}

// async global->LDS, 16B per lane (wave-uniform LDS base + lane*16 layout)
__device__ __forceinline__ void async_ld16(const void* g, void* l) {
    __builtin_amdgcn_global_load_lds(
        (const __attribute__((address_space(1))) u32*)g,
        (__attribute__((address_space(3))) u32*)l, 16, 0, 0);
}

// ---------------------------------------------------------------------------
// All weight transposes in one dispatch. Flat tile id -> {weight, tile}.
// Per layer: qkv 24x8=192 | fc 8x8=64 | ff1 32x8=256 | ff2 8x32=256  => 768.
// ---------------------------------------------------------------------------
__global__ __launch_bounds__(256)
void wconv_all(const float* __restrict__ qkv_w, const float* __restrict__ fc_w,
               const float* __restrict__ ff1_w, const float* __restrict__ ff2_w,
               ushort* __restrict__ wq, ushort* __restrict__ wfc,
               ushort* __restrict__ wf1, ushort* __restrict__ wf2)
{
    const int l = blockIdx.z;
    int t = blockIdx.x;
    const float* src; ushort* dst; int K, N, nx;
    if (t < 192)      {          src = qkv_w; dst = wq;  K = 256;  N = 768;  nx = 24; }
    else if (t < 256) { t -= 192; src = fc_w;  dst = wfc; K = 256;  N = 256;  nx = 8; }
    else if (t < 512) { t -= 256; src = ff1_w; dst = wf1; K = 256;  N = 1024; nx = 32; }
    else              { t -= 512; src = ff2_w; dst = wf2; K = 1024; N = 256;  nx = 8; }
    src += (size_t)l * K * N;
    dst += (size_t)l * K * N;
    const int n0 = (t % nx) * 32, k0 = (t / nx) * 32;

    __shared__ ushort tt[32][33];
    const int tn = threadIdx.x & 31, tk8 = threadIdx.x >> 5;
    #pragma unroll
    for (int i = 0; i < 4; ++i)
        tt[tn][tk8 + i * 8] = f2bf(src[(size_t)(k0 + tk8 + i * 8) * N + n0 + tn]);
    __syncthreads();
    #pragma unroll
    for (int i = 0; i < 4; ++i)
        dst[(size_t)(n0 + tk8 + i * 8) * K + k0 + tn] = tt[tk8 + i * 8][tn];
}

// ---------------------------------------------------------------------------
// x_in fp32 -> x fp32 (d_out residual stream) + x_bf bf16 mirror
// ---------------------------------------------------------------------------
__global__ __launch_bounds__(256)
void convert_x(const float* __restrict__ xin, float* __restrict__ x,
               ushort* __restrict__ xb)
{
    const size_t i = ((size_t)blockIdx.x * 256 + threadIdx.x) * 4;
    const float4 v = *reinterpret_cast<const float4*>(xin + i);
    *reinterpret_cast<float4*>(x + i) = v;
    uint2 p = make_uint2(pack2(v.x, v.y), pack2(v.z, v.w));
    *reinterpret_cast<uint2*>(xb + i) = p;
}

// ---------------------------------------------------------------------------
// MFMA GEMM: C[M,N] = A[M,K](bf16) @ WT[N,K](bf16)^T + bias, opt ReLU.
// Template geometry: BM x BN tile, 4 waves arranged WM x WN. (round-4 verified)
// ---------------------------------------------------------------------------
template<int BM, int BN, int WM, int WN, int ACT, int OBF>
__global__ __launch_bounds__(256)
void gemm_mfma(const ushort* __restrict__ A, const ushort* __restrict__ WT,
               const float* __restrict__ bias, float* __restrict__ Cf,
               ushort* __restrict__ Cb, int N, int K)
{
    constexpr int BK = 64;
    constexpr int WR = BM / WM;
    constexpr int WC = BN / WN;
    constexpr int MR = WR / 16, NR = WC / 16;
    __shared__ __align__(16) ushort As[BM * BK];
    __shared__ __align__(16) ushort Bs[BN * BK];

    const int tid = threadIdx.x;
    const int m0 = blockIdx.y * BM, n0 = blockIdx.x * BN;
    const int wid = tid >> 6, lane = tid & 63;
    const int g = lane >> 4, c = lane & 15;
    const int wr = wid / WN, wc = wid % WN;

    f32x4 acc[MR][NR] = {};

    for (int k0 = 0; k0 < K; k0 += BK) {
        #pragma unroll
        for (int it = 0; it < (BM * BK * 2) / 4096; ++it) {
            const int o = tid * 16 + it * 4096;
            const int r = o >> 7, cb = o & 127;
            async_ld16(A + (size_t)(m0 + r) * K + k0 + (cb >> 1), (char*)As + o);
        }
        #pragma unroll
        for (int it = 0; it < (BN * BK * 2) / 4096; ++it) {
            const int o = tid * 16 + it * 4096;
            const int r = o >> 7, cb = o & 127;
            async_ld16(WT + (size_t)(n0 + r) * K + k0 + (cb >> 1), (char*)Bs + o);
        }
        __syncthreads();

        #pragma unroll
        for (int ks = 0; ks < 2; ++ks) {
            bf16x8 af[MR], bfr[NR];
            #pragma unroll
            for (int mi = 0; mi < MR; ++mi)
                af[mi] = *(const bf16x8*)&As[(wr * WR + mi * 16 + c) * BK + ks * 32 + g * 8];
            #pragma unroll
            for (int ni = 0; ni < NR; ++ni)
                bfr[ni] = *(const bf16x8*)&Bs[(wc * WC + ni * 16 + c) * BK + ks * 32 + g * 8];
            #pragma unroll
            for (int mi = 0; mi < MR; ++mi)
                #pragma unroll
                for (int ni = 0; ni < NR; ++ni)
                    acc[mi][ni] = __builtin_amdgcn_mfma_f32_16x16x32_bf16(
                        af[mi], bfr[ni], acc[mi][ni], 0, 0, 0);
        }
        __syncthreads();
    }

    float bv[NR];
    #pragma unroll
    for (int ni = 0; ni < NR; ++ni)
        bv[ni] = bias[n0 + wc * WC + ni * 16 + c];

    #pragma unroll
    for (int mi = 0; mi < MR; ++mi) {
        #pragma unroll
        for (int j = 0; j < 4; ++j) {
            const int row = m0 + wr * WR + mi * 16 + g * 4 + j;
            #pragma unroll
            for (int ni = 0; ni < NR; ++ni) {
                float v = acc[mi][ni][j] + bv[ni];
                if (ACT) v = fmaxf(v, 0.f);
                const int col = n0 + wc * WC + ni * 16 + c;
                if (OBF) Cb[(size_t)row * N + col] = f2bf(v);
                else     Cf[(size_t)row * N + col] = v;
            }
        }
    }
}

// ---------------------------------------------------------------------------
// Fused fc GEMM + residual add + LayerNorm1.  Full-row tile: BM=64 x BN=256,
// 512 threads (8 waves, 2x4), K=256.  Writes x (fp32) and x_bf (bf16).
// LN reduction: per-lane partials -> shfl over 16 lanes -> LDS cross-wave.
// ---------------------------------------------------------------------------
__global__ __launch_bounds__(512)
void fc_ln(const ushort* __restrict__ A, const ushort* __restrict__ WT,
           const float* __restrict__ bias, const float* __restrict__ lg,
           const float* __restrict__ lb, float* __restrict__ x,
           ushort* __restrict__ xb)
{
    constexpr int BM = 64, BN = 256, BK = 64, K = 256, N = 256;
    __shared__ __align__(16) ushort As[BM * BK];
    __shared__ __align__(16) ushort Bs[BN * BK];
    __shared__ float rsum[4][64], rsq[4][64], mval[64], ival[64];

    const int tid = threadIdx.x;
    const int m0 = blockIdx.x * BM;
    const int wid = tid >> 6, lane = tid & 63;
    const int g = lane >> 4, c = lane & 15;
    const int wr = wid >> 2, wc = wid & 3;    // waves 2x4; wave tile 32x64

    f32x4 acc[2][4] = {};

    for (int k0 = 0; k0 < K; k0 += BK) {
        {   // A: 8KB = 512 x 16B
            const int o = tid * 16;
            const int r = o >> 7, cb = o & 127;
            async_ld16(A + (size_t)(m0 + r) * K + k0 + (cb >> 1), (char*)As + o);
        }
        #pragma unroll
        for (int it = 0; it < 4; ++it) {   // B: 32KB
            const int o = tid * 16 + it * 8192;
            const int r = o >> 7, cb = o & 127;
            async_ld16(WT + (size_t)r * K + k0 + (cb >> 1), (char*)Bs + o);
        }
        __syncthreads();

        #pragma unroll
        for (int ks = 0; ks < 2; ++ks) {
            bf16x8 af[2], bfr[4];
            #pragma unroll
            for (int mi = 0; mi < 2; ++mi)
                af[mi] = *(const bf16x8*)&As[(wr * 32 + mi * 16 + c) * BK + ks * 32 + g * 8];
            #pragma unroll
            for (int ni = 0; ni < 4; ++ni)
                bfr[ni] = *(const bf16x8*)&Bs[(wc * 64 + ni * 16 + c) * BK + ks * 32 + g * 8];
            #pragma unroll
            for (int mi = 0; mi < 2; ++mi)
                #pragma unroll
                for (int ni = 0; ni < 4; ++ni)
                    acc[mi][ni] = __builtin_amdgcn_mfma_f32_16x16x32_bf16(
                        af[mi], bfr[ni], acc[mi][ni], 0, 0, 0);
        }
        __syncthreads();
    }

    // ---- epilogue: v = acc + bias + residual; row mean/var; LN; store
    float bv[4], gl[4], bl[4];
    #pragma unroll
    for (int ni = 0; ni < 4; ++ni) {
        const int col = wc * 64 + ni * 16 + c;
        bv[ni] = bias[col]; gl[ni] = lg[col]; bl[ni] = lb[col];
    }

    #pragma unroll
    for (int mi = 0; mi < 2; ++mi) {
        #pragma unroll
        for (int j = 0; j < 4; ++j) {
            const int row = wr * 32 + mi * 16 + g * 4 + j;
            float s = 0.f, q = 0.f;
            #pragma unroll
            for (int ni = 0; ni < 4; ++ni) {
                const int col = wc * 64 + ni * 16 + c;
                float vv = acc[mi][ni][j] + bv[ni] + x[(size_t)(m0 + row) * N + col];
                acc[mi][ni][j] = vv;
                s += vv; q += vv * vv;
            }
            #pragma unroll
            for (int off = 1; off < 16; off <<= 1) {
                s += __shfl_xor(s, off);
                q += __shfl_xor(q, off);
            }
            if (c == 0) { rsum[wc][row] = s; rsq[wc][row] = q; }
        }
    }
    __syncthreads();
    if (tid < 64) {
        const float s = rsum[0][tid] + rsum[1][tid] + rsum[2][tid] + rsum[3][tid];
        const float q = rsq[0][tid] + rsq[1][tid] + rsq[2][tid] + rsq[3][tid];
        const float mean = s * (1.f / N);
        const float var = q * (1.f / N) - mean * mean;
        mval[tid] = mean;
        ival[tid] = rsqrtf(var + LN_EPS);
    }
    __syncthreads();
    #pragma unroll
    for (int mi = 0; mi < 2; ++mi) {
        #pragma unroll
        for (int j = 0; j < 4; ++j) {
            const int row = wr * 32 + mi * 16 + g * 4 + j;
            const float mean = mval[row], inv = ival[row];
            #pragma unroll
            for (int ni = 0; ni < 4; ++ni) {
                const int col = wc * 64 + ni * 16 + c;
                const float y = (acc[mi][ni][j] - mean) * inv * gl[ni] + bl[ni];
                x[(size_t)(m0 + row) * N + col] = y;
                xb[(size_t)(m0 + row) * N + col] = f2bf(y);
            }
        }
    }
}

// ---------------------------------------------------------------------------
// Flash attention v3: 512 threads = 8 waves, QBLK=128 (one 16-q tile/wave),
// KVBLK=64 double-buffered.  Staging role-split: waves 0-3 stage K via
// global_load_lds, waves 4-7 gather V to regs and commit transposed.
// Swapped QK^T (S^T = mfma(K,Q)): per-lane scalar softmax state (q = lane&15).
// Math identical to round-4 verified kernel.
// ---------------------------------------------------------------------------
__global__ __launch_bounds__(512)
void attn_mfma3(const ushort* __restrict__ qkv, const int* __restrict__ mask,
                ushort* __restrict__ out)
{
    const int tid = threadIdx.x;
    const int lane = tid & 63, wid = tid >> 6;
    const int g = lane >> 4, c = lane & 15;
    const int qb = blockIdx.x & 7;            // 8 q-blocks of 128
    const int bh = blockIdx.x >> 3;           // 0..31
    const int h = bh & (NH - 1), b = bh >> 3;
    const int q0 = qb * 128 + wid * 16;

    __shared__ __align__(16) ushort Kb[2][64 * 32];   // [key][d] rows 64B
    __shared__ __align__(16) ushort Vt[2][32][72];    // [d][key] stride 144B
    __shared__ __align__(16) ushort Pl[8][16][40];    // per-wave [q][key]
    __shared__ __align__(16) float  sbias[SS];

    const ushort* base = qkv + (size_t)b * SS * 768;

    {   // mask bias
        const int i = tid * 2;
        const int2 mv = *reinterpret_cast<const int2*>(mask + b * SS + i);
        float2 bv;
        bv.x = mv.x ? 0.f : -3.4e38f;
        bv.y = mv.y ? 0.f : -3.4e38f;
        *reinterpret_cast<float2*>(&sbias[i]) = bv;
    }

    const bf16x8 qfrag = *(const bf16x8*)(
        base + (size_t)(q0 + c) * 768 + h * HDIM + g * 8);

    const bool kRole = (tid < 256);
    const int kkey = tid >> 2, kdq = tid & 3;     // K staging (waves 0-3)
    const int vtid = tid - 256;
    const int vd = vtid & 31, vkg = vtid >> 5;    // V staging (waves 4-7)
    ushort vreg[8];

    // ---- prologue: stage chunk 0
    if (kRole) {
        async_ld16(base + (size_t)kkey * 768 + DMODEL + h * HDIM + kdq * 8,
                   (char*)&Kb[0][0] + tid * 16);
    } else {
        const ushort* vp = base + (size_t)(vkg * 8) * 768 + 2 * DMODEL + h * HDIM + vd;
        #pragma unroll
        for (int u = 0; u < 8; ++u) vreg[u] = vp[u * 768];
        uint4 pk;
        pk.x = vreg[0] | ((uint)vreg[1] << 16);
        pk.y = vreg[2] | ((uint)vreg[3] << 16);
        pk.z = vreg[4] | ((uint)vreg[5] << 16);
        pk.w = vreg[6] | ((uint)vreg[7] << 16);
        *reinterpret_cast<uint4*>(&Vt[0][vd][vkg * 8]) = pk;
    }
    __syncthreads();

    float m = -1e30f, lsum = 0.f;
    f32x4 o0 = {0.f, 0.f, 0.f, 0.f}, o1 = {0.f, 0.f, 0.f, 0.f};
    const f32x4 zf = {0.f, 0.f, 0.f, 0.f};

    for (int t = 0; t < 16; ++t) {
        const int cur = t & 1;
        if (t < 15) {
            const int tn = t + 1;
            if (kRole) {
                async_ld16(base + (size_t)(tn * 64 + kkey) * 768 + DMODEL + h * HDIM + kdq * 8,
                           (char*)&Kb[tn & 1][0] + tid * 16);
            } else {
                const ushort* vp = base + (size_t)(tn * 64 + vkg * 8) * 768
                                   + 2 * DMODEL + h * HDIM + vd;
                #pragma unroll
                for (int u = 0; u < 8; ++u) vreg[u] = vp[u * 768];
            }
        }

        // ---- S^T tiles: rows = keys (4/lane), cols = q (=c)
        f32x4 s[4];
        #pragma unroll
        for (int kt = 0; kt < 4; ++kt) {
            const bf16x8 kf = *(const bf16x8*)&Kb[cur][(kt * 16 + c) * 32 + g * 8];
            s[kt] = __builtin_amdgcn_mfma_f32_16x16x32_bf16(kf, qfrag, zf, 0, 0, 0);
        }
        #pragma unroll
        for (int kt = 0; kt < 4; ++kt) {
            const f32x4 bv = *reinterpret_cast<const f32x4*>(
                &sbias[t * 64 + kt * 16 + g * 4]);
            #pragma unroll
            for (int r = 0; r < 4; ++r) s[kt][r] += bv[r];
        }

        // ---- online softmax (per-lane state, q = c)
        float mx = fmaxf(fmaxf(s[0][0], s[0][1]), fmaxf(s[0][2], s[0][3]));
        #pragma unroll
        for (int kt = 1; kt < 4; ++kt)
            mx = fmaxf(mx, fmaxf(fmaxf(s[kt][0], s[kt][1]),
                                 fmaxf(s[kt][2], s[kt][3])));
        mx = fmaxf(mx, __shfl_xor(mx, 16));
        mx = fmaxf(mx, __shfl_xor(mx, 32));
        const float mn = fmaxf(m, mx);
        const float sc = __expf(m - mn);
        m = mn;

        float ls = 0.f;
        #pragma unroll
        for (int kt = 0; kt < 4; ++kt) {
            const float p0 = __expf(s[kt][0] - mn);
            const float p1 = __expf(s[kt][1] - mn);
            const float p2 = __expf(s[kt][2] - mn);
            const float p3 = __expf(s[kt][3] - mn);
            ls += (p0 + p1) + (p2 + p3);
            uint2 pk2 = make_uint2(pack2(p0, p1), pack2(p2, p3));
            *reinterpret_cast<uint2*>(&Pl[wid][c][kt * 16 + g * 4]) = pk2;
        }
        ls += __shfl_xor(ls, 16);
        ls += __shfl_xor(ls, 32);
        lsum = lsum * sc + ls;

        // ---- rescale O (rows q = g*4+r; scale lives at lane q=c)
        float scr[4];
        #pragma unroll
        for (int r = 0; r < 4; ++r) scr[r] = __shfl(sc, g * 4 + r);
        #pragma unroll
        for (int r = 0; r < 4; ++r) { o0[r] *= scr[r]; o1[r] *= scr[r]; }

        // ---- PV: O[16q][32d] += P[16q][64k] @ V[64k][32d]
        #pragma unroll
        for (int ks = 0; ks < 2; ++ks) {
            const bf16x8 pa = *(const bf16x8*)&Pl[wid][c][ks * 32 + g * 8];
            const bf16x8 v0 = *(const bf16x8*)&Vt[cur][c][ks * 32 + g * 8];
            const bf16x8 v1 = *(const bf16x8*)&Vt[cur][16 + c][ks * 32 + g * 8];
            o0 = __builtin_amdgcn_mfma_f32_16x16x32_bf16(pa, v0, o0, 0, 0, 0);
            o1 = __builtin_amdgcn_mfma_f32_16x16x32_bf16(pa, v1, o1, 0, 0, 0);
        }

        if (t < 15 && !kRole) {   // commit V(t+1)
            uint4 pk;
            pk.x = vreg[0] | ((uint)vreg[1] << 16);
            pk.y = vreg[2] | ((uint)vreg[3] << 16);
            pk.z = vreg[4] | ((uint)vreg[5] << 16);
            pk.w = vreg[6] | ((uint)vreg[7] << 16);
            *reinterpret_cast<uint4*>(&Vt[(t + 1) & 1][vd][vkg * 8]) = pk;
        }
        __syncthreads();
    }

    // ---- finalize
    const float rs = 1.f / lsum;
    float inv[4];
    #pragma unroll
    for (int r = 0; r < 4; ++r) inv[r] = __shfl(rs, g * 4 + r);
    #pragma unroll
    for (int r = 0; r < 4; ++r) {
        ushort* op = out + (size_t)(b * SS + q0 + g * 4 + r) * DMODEL + h * HDIM;
        op[c]      = f2bf(o0[r] * inv[r]);
        op[16 + c] = f2bf(o1[r] * inv[r]);
    }
}

// ---------------------------------------------------------------------------
// x = LayerNorm(a + x) * g + beta; also writes bf16 mirror xb. (for LN2)
// ---------------------------------------------------------------------------
__global__ __launch_bounds__(256)
void add_ln_kernel(const float* __restrict__ a, const float* __restrict__ r,
                   const float* __restrict__ g, const float* __restrict__ beta,
                   float* __restrict__ out, ushort* __restrict__ xb)
{
    const int wave = threadIdx.x >> 6;
    const int lane = threadIdx.x & 63;
    const int row = blockIdx.x * 4 + wave;
    const size_t off = (size_t)row * DMODEL + lane * 4;

    const float4 va = *reinterpret_cast<const float4*>(a + off);
    const float4 vr = *reinterpret_cast<const float4*>(r + off);
    float v[4] = { va.x + vr.x, va.y + vr.y, va.z + vr.z, va.w + vr.w };

    float s = v[0] + v[1] + v[2] + v[3];
    #pragma unroll
    for (int o = 32; o >= 1; o >>= 1) s += __shfl_xor(s, o);
    const float mean = s * (1.f / DMODEL);

    float d0 = v[0] - mean, d1 = v[1] - mean, d2 = v[2] - mean, d3 = v[3] - mean;
    float sq = d0 * d0 + d1 * d1 + d2 * d2 + d3 * d3;
    #pragma unroll
    for (int o = 32; o >= 1; o >>= 1) sq += __shfl_xor(sq, o);
    const float inv = rsqrtf(sq * (1.f / DMODEL) + LN_EPS);

    const float4 vg = *reinterpret_cast<const float4*>(g + lane * 4);
    const float4 vb = *reinterpret_cast<const float4*>(beta + lane * 4);
    float4 o4;
    o4.x = d0 * inv * vg.x + vb.x;
    o4.y = d1 * inv * vg.y + vb.y;
    o4.z = d2 * inv * vg.z + vb.z;
    o4.w = d3 * inv * vg.w + vb.w;
    *reinterpret_cast<float4*>(out + off) = o4;
    *reinterpret_cast<uint2*>(xb + off) =
        make_uint2(pack2(o4.x, o4.y), pack2(o4.z, o4.w));
}

// ---------------------------------------------------------------------------
extern "C" void kernel_launch(void* const* d_in, const int* in_sizes, int n_in,
                              void* d_out, int out_size, void* d_ws, size_t ws_size,
                              hipStream_t stream)
{
    const float* x_in   = (const float*)d_in[0];
    const int*   maskp  = (const int*)d_in[1];
    const float* qkv_w  = (const float*)d_in[2];
    const float* qkv_b  = (const float*)d_in[3];
    const float* fc_w   = (const float*)d_in[4];
    const float* fc_b   = (const float*)d_in[5];
    const float* ln1_g  = (const float*)d_in[6];
    const float* ln1_b  = (const float*)d_in[7];
    const float* ln2_g  = (const float*)d_in[8];
    const float* ln2_b  = (const float*)d_in[9];
    const float* ff1_w  = (const float*)d_in[10];
    const float* ff1_b  = (const float*)d_in[11];
    const float* ff2_w  = (const float*)d_in[12];
    const float* ff2_b  = (const float*)d_in[13];

    float* x = (float*)d_out;                       // [4096,256] fp32 residual

    ushort* wt_qkv = (ushort*)d_ws;                 // [L][768][256]
    ushort* wt_fc  = wt_qkv + (size_t)NL * 768 * 256;
    ushort* wt_ff1 = wt_fc  + (size_t)NL * 256 * 256;
    ushort* wt_ff2 = wt_ff1 + (size_t)NL * 1024 * 256;
    ushort* big    = wt_ff2 + (size_t)NL * 256 * 1024;  // qkv_bf / h_bf (8MB)
    ushort* attn_bf= big + (size_t)MROWS * FFDIM;
    ushort* x_bf   = attn_bf + (size_t)MROWS * DMODEL;
    float*  o2     = (float*)(x_bf + (size_t)MROWS * DMODEL);

    wconv_all<<<dim3(768, 1, NL), 256, 0, stream>>>(
        qkv_w, fc_w, ff1_w, ff2_w, wt_qkv, wt_fc, wt_ff1, wt_ff2);
    convert_x<<<dim3(MROWS * DMODEL / 1024), 256, 0, stream>>>(x_in, x, x_bf);

    for (int l = 0; l < NL; ++l) {
        // qkv (bf16 out) [4096,768]
        gemm_mfma<64, 128, 2, 2, 0, 1><<<dim3(6, 64), 256, 0, stream>>>(
            x_bf, wt_qkv + (size_t)l * 768 * 256, qkv_b + l * 768,
            nullptr, big, 768, 256);
        // attention -> attn_bf [4096,256] bf16
        attn_mfma3<<<dim3(256), 512, 0, stream>>>(big, maskp, attn_bf);
        // x = LN1(attn @ fc_w + b + x)   (fused)
        fc_ln<<<dim3(64), 512, 0, stream>>>(
            attn_bf, wt_fc + (size_t)l * 256 * 256, fc_b + l * 256,
            ln1_g + l * DMODEL, ln1_b + l * DMODEL, x, x_bf);
        // h = relu(x @ ff1_w + b) (bf16 out) [4096,1024]
        gemm_mfma<128, 128, 2, 2, 1, 1><<<dim3(8, 32), 256, 0, stream>>>(
            x_bf, wt_ff1 + (size_t)l * 1024 * 256, ff1_b + l * FFDIM,
            nullptr, big, 1024, 256);
        // o2 = h @ ff2_w + b (fp32 out)
        gemm_mfma<64, 64, 2, 2, 0, 0><<<dim3(4, 64), 256, 0, stream>>>(
            big, wt_ff2 + (size_t)l * 256 * 1024, ff2_b + l * DMODEL,
            o2, nullptr, 256, 1024);
        // x = LN2(x + o2)
        add_ln_kernel<<<dim3(MROWS / 4), 256, 0, stream>>>(
            o2, x, ln2_g + l * DMODEL, ln2_b + l * DMODEL, x, x_bf);
    }
}

// Round 6
// 298.721 us; speedup vs baseline: 1.0718x; 1.0718x over previous
//
#include <hip/hip_runtime.h>
#include <hip/hip_bf16.h>
#include <math.h>

#define NL 4
#define DMODEL 256
#define NH 8
#define FFDIM 1024
#define BB 4
#define SS 1024
#define HDIM 32
#define MROWS (BB * SS)   // 4096
#define LN_EPS 1e-5f

typedef __bf16 bf16x8 __attribute__((ext_vector_type(8)));
typedef float f32x4 __attribute__((ext_vector_type(4)));
typedef short s16x4 __attribute__((ext_vector_type(4)));
typedef unsigned int u32;

__device__ __forceinline__ ushort f2bf(float f) {
    uint u = __builtin_bit_cast(uint, f);
    u += 0x7fff + ((u >> 16) & 1);          // round-to-nearest-even
    return (ushort)(u >> 16);
}
__device__ __forceinline__ uint pack2(float a, float b) {
    return (uint)f2bf(a) | ((uint)f2bf(b) << 16);
}

// async global->LDS, 16B per lane (wave-uniform LDS base + lane*16 layout)
__device__ __forceinline__ void async_ld16(const void* g, void* l) {
    __builtin_amdgcn_global_load_lds(
        (const __attribute__((address_space(1))) u32*)g,
        (__attribute__((address_space(3))) u32*)l, 16, 0, 0);
}

// ds_read_b64_tr_b16: per-lane byte addr A -> 4 bf16 at A, A+32B, A+64B, A+96B
#if __has_builtin(__builtin_amdgcn_ds_read_tr16_b64)
#define TR_BUILTIN 1
#else
#define TR_BUILTIN 0
#endif

__device__ __forceinline__ s16x4 tr16(const ushort* p) {
    __attribute__((address_space(3))) s16x4* ap =
        (__attribute__((address_space(3))) s16x4*)p;
#if TR_BUILTIN
    return __builtin_amdgcn_ds_read_tr16_b64(ap);
#else
    s16x4 r;
    asm volatile("ds_read_b64_tr_b16 %0, %1" : "=v"(r) : "v"(ap) : "memory");
    return r;
#endif
}
__device__ __forceinline__ void tr_fence() {
#if !TR_BUILTIN
    asm volatile("s_waitcnt lgkmcnt(0)" ::: "memory");
    __builtin_amdgcn_sched_barrier(0);
#endif
}

// ---------------------------------------------------------------------------
// All weight transposes in one dispatch. Flat tile id -> {weight, tile}.
// ---------------------------------------------------------------------------
__global__ __launch_bounds__(256)
void wconv_all(const float* __restrict__ qkv_w, const float* __restrict__ fc_w,
               const float* __restrict__ ff1_w, const float* __restrict__ ff2_w,
               ushort* __restrict__ wq, ushort* __restrict__ wfc,
               ushort* __restrict__ wf1, ushort* __restrict__ wf2)
{
    const int l = blockIdx.z;
    int t = blockIdx.x;
    const float* src; ushort* dst; int K, N, nx;
    if (t < 192)      {          src = qkv_w; dst = wq;  K = 256;  N = 768;  nx = 24; }
    else if (t < 256) { t -= 192; src = fc_w;  dst = wfc; K = 256;  N = 256;  nx = 8; }
    else if (t < 512) { t -= 256; src = ff1_w; dst = wf1; K = 256;  N = 1024; nx = 32; }
    else              { t -= 512; src = ff2_w; dst = wf2; K = 1024; N = 256;  nx = 8; }
    src += (size_t)l * K * N;
    dst += (size_t)l * K * N;
    const int n0 = (t % nx) * 32, k0 = (t / nx) * 32;

    __shared__ ushort tt[32][33];
    const int tn = threadIdx.x & 31, tk8 = threadIdx.x >> 5;
    #pragma unroll
    for (int i = 0; i < 4; ++i)
        tt[tn][tk8 + i * 8] = f2bf(src[(size_t)(k0 + tk8 + i * 8) * N + n0 + tn]);
    __syncthreads();
    #pragma unroll
    for (int i = 0; i < 4; ++i)
        dst[(size_t)(n0 + tk8 + i * 8) * K + k0 + tn] = tt[tk8 + i * 8][tn];
}

// ---------------------------------------------------------------------------
// x_in fp32 -> x fp32 (d_out residual stream) + x_bf bf16 mirror
// ---------------------------------------------------------------------------
__global__ __launch_bounds__(256)
void convert_x(const float* __restrict__ xin, float* __restrict__ x,
               ushort* __restrict__ xb)
{
    const size_t i = ((size_t)blockIdx.x * 256 + threadIdx.x) * 4;
    const float4 v = *reinterpret_cast<const float4*>(xin + i);
    *reinterpret_cast<float4*>(x + i) = v;
    uint2 p = make_uint2(pack2(v.x, v.y), pack2(v.z, v.w));
    *reinterpret_cast<uint2*>(xb + i) = p;
}

// ---------------------------------------------------------------------------
// MFMA GEMM: C[M,N] = A[M,K](bf16) @ WT[N,K](bf16)^T + bias, opt ReLU.
// (round-4 verified structure)
// ---------------------------------------------------------------------------
template<int BM, int BN, int WM, int WN, int ACT, int OBF>
__global__ __launch_bounds__(256)
void gemm_mfma(const ushort* __restrict__ A, const ushort* __restrict__ WT,
               const float* __restrict__ bias, float* __restrict__ Cf,
               ushort* __restrict__ Cb, int N, int K)
{
    constexpr int BK = 64;
    constexpr int WR = BM / WM;
    constexpr int WC = BN / WN;
    constexpr int MR = WR / 16, NR = WC / 16;
    __shared__ __align__(16) ushort As[BM * BK];
    __shared__ __align__(16) ushort Bs[BN * BK];

    const int tid = threadIdx.x;
    const int m0 = blockIdx.y * BM, n0 = blockIdx.x * BN;
    const int wid = tid >> 6, lane = tid & 63;
    const int g = lane >> 4, c = lane & 15;
    const int wr = wid / WN, wc = wid % WN;

    f32x4 acc[MR][NR] = {};

    for (int k0 = 0; k0 < K; k0 += BK) {
        #pragma unroll
        for (int it = 0; it < (BM * BK * 2) / 4096; ++it) {
            const int o = tid * 16 + it * 4096;
            const int r = o >> 7, cb = o & 127;
            async_ld16(A + (size_t)(m0 + r) * K + k0 + (cb >> 1), (char*)As + o);
        }
        #pragma unroll
        for (int it = 0; it < (BN * BK * 2) / 4096; ++it) {
            const int o = tid * 16 + it * 4096;
            const int r = o >> 7, cb = o & 127;
            async_ld16(WT + (size_t)(n0 + r) * K + k0 + (cb >> 1), (char*)Bs + o);
        }
        __syncthreads();

        #pragma unroll
        for (int ks = 0; ks < 2; ++ks) {
            bf16x8 af[MR], bfr[NR];
            #pragma unroll
            for (int mi = 0; mi < MR; ++mi)
                af[mi] = *(const bf16x8*)&As[(wr * WR + mi * 16 + c) * BK + ks * 32 + g * 8];
            #pragma unroll
            for (int ni = 0; ni < NR; ++ni)
                bfr[ni] = *(const bf16x8*)&Bs[(wc * WC + ni * 16 + c) * BK + ks * 32 + g * 8];
            #pragma unroll
            for (int mi = 0; mi < MR; ++mi)
                #pragma unroll
                for (int ni = 0; ni < NR; ++ni)
                    acc[mi][ni] = __builtin_amdgcn_mfma_f32_16x16x32_bf16(
                        af[mi], bfr[ni], acc[mi][ni], 0, 0, 0);
        }
        __syncthreads();
    }

    float bv[NR];
    #pragma unroll
    for (int ni = 0; ni < NR; ++ni)
        bv[ni] = bias[n0 + wc * WC + ni * 16 + c];

    #pragma unroll
    for (int mi = 0; mi < MR; ++mi) {
        #pragma unroll
        for (int j = 0; j < 4; ++j) {
            const int row = m0 + wr * WR + mi * 16 + g * 4 + j;
            #pragma unroll
            for (int ni = 0; ni < NR; ++ni) {
                float v = acc[mi][ni][j] + bv[ni];
                if (ACT) v = fmaxf(v, 0.f);
                const int col = n0 + wc * WC + ni * 16 + c;
                if (OBF) Cb[(size_t)row * N + col] = f2bf(v);
                else     Cf[(size_t)row * N + col] = v;
            }
        }
    }
}

// ---------------------------------------------------------------------------
// Fused fc GEMM + residual + LayerNorm1.  BM=16 x BN=256 (full row), 256
// blocks x 256 threads (4 waves, 1x4) -> full chip fill.  K=256.
// ---------------------------------------------------------------------------
__global__ __launch_bounds__(256)
void fc_ln(const ushort* __restrict__ A, const ushort* __restrict__ WT,
           const float* __restrict__ bias, const float* __restrict__ lg,
           const float* __restrict__ lb, float* __restrict__ x,
           ushort* __restrict__ xb)
{
    constexpr int BK = 64, K = 256, N = 256;
    __shared__ __align__(16) ushort As[16 * BK];
    __shared__ __align__(16) ushort Bs[N * BK];
    __shared__ float rsum[4][16], rsq[4][16], mval[16], ival[16];

    const int tid = threadIdx.x;
    const int m0 = blockIdx.x * 16;
    const int wid = tid >> 6, lane = tid & 63;
    const int g = lane >> 4, c = lane & 15;

    f32x4 acc[4] = {};

    for (int k0 = 0; k0 < K; k0 += BK) {
        if (tid < 128) {   // A: 2KB
            const int o = tid * 16;
            async_ld16(A + (size_t)(m0 + (o >> 7)) * K + k0 + ((o & 127) >> 1),
                       (char*)As + o);
        }
        #pragma unroll
        for (int it = 0; it < 8; ++it) {   // B: 32KB
            const int o = tid * 16 + it * 4096;
            async_ld16(WT + (size_t)(o >> 7) * K + k0 + ((o & 127) >> 1),
                       (char*)Bs + o);
        }
        __syncthreads();

        #pragma unroll
        for (int ks = 0; ks < 2; ++ks) {
            const bf16x8 af = *(const bf16x8*)&As[c * BK + ks * 32 + g * 8];
            #pragma unroll
            for (int ni = 0; ni < 4; ++ni) {
                const bf16x8 bf = *(const bf16x8*)&Bs[(wid * 64 + ni * 16 + c) * BK + ks * 32 + g * 8];
                acc[ni] = __builtin_amdgcn_mfma_f32_16x16x32_bf16(af, bf, acc[ni], 0, 0, 0);
            }
        }
        __syncthreads();
    }

    float bv[4], glv[4], blv[4];
    #pragma unroll
    for (int ni = 0; ni < 4; ++ni) {
        const int col = wid * 64 + ni * 16 + c;
        bv[ni] = bias[col]; glv[ni] = lg[col]; blv[ni] = lb[col];
    }

    #pragma unroll
    for (int j = 0; j < 4; ++j) {
        const int row = g * 4 + j;
        float s = 0.f, q = 0.f;
        #pragma unroll
        for (int ni = 0; ni < 4; ++ni) {
            const int col = wid * 64 + ni * 16 + c;
            float vv = acc[ni][j] + bv[ni] + x[(size_t)(m0 + row) * N + col];
            acc[ni][j] = vv;
            s += vv; q += vv * vv;
        }
        #pragma unroll
        for (int off = 1; off < 16; off <<= 1) {
            s += __shfl_xor(s, off);
            q += __shfl_xor(q, off);
        }
        if (c == 0) { rsum[wid][row] = s; rsq[wid][row] = q; }
    }
    __syncthreads();
    if (tid < 16) {
        const float s = rsum[0][tid] + rsum[1][tid] + rsum[2][tid] + rsum[3][tid];
        const float q = rsq[0][tid] + rsq[1][tid] + rsq[2][tid] + rsq[3][tid];
        const float mean = s * (1.f / N);
        const float var = q * (1.f / N) - mean * mean;
        mval[tid] = mean;
        ival[tid] = rsqrtf(var + LN_EPS);
    }
    __syncthreads();
    #pragma unroll
    for (int j = 0; j < 4; ++j) {
        const int row = g * 4 + j;
        const float mean = mval[row], inv = ival[row];
        #pragma unroll
        for (int ni = 0; ni < 4; ++ni) {
            const int col = wid * 64 + ni * 16 + c;
            const float y = (acc[ni][j] - mean) * inv * glv[ni] + blv[ni];
            x[(size_t)(m0 + row) * N + col] = y;
            xb[(size_t)(m0 + row) * N + col] = f2bf(y);
        }
    }
}

// ---------------------------------------------------------------------------
// Flash attention v4: 4 waves/block, QBLK=64, KVBLK=64 double-buffered,
// 512 blocks.  K staged async with 16B-granule XOR swizzle (^(row&3)<<4).
// V staged async LINEAR as [d-half][key][16] (32B rows) and consumed via
// ds_read_b64_tr_b16 (per-lane addr A -> elems A,+32B,+64B,+96B = column c,
// keys 8g..8g+3).  Swapped QK^T; per-lane scalar softmax state (q = lane&15).
// Math identical to round-4 verified kernel.
// ---------------------------------------------------------------------------
__global__ __launch_bounds__(256)
void attn_mfma4(const ushort* __restrict__ qkv, const int* __restrict__ mask,
                ushort* __restrict__ out)
{
    const int tid = threadIdx.x;
    const int lane = tid & 63, wid = tid >> 6;
    const int g = lane >> 4, c = lane & 15;
    const int qblk = blockIdx.x & 15;          // 16 q-blocks of 64
    const int bh = blockIdx.x >> 4;            // 0..31
    const int h = bh & (NH - 1), b = bh >> 3;
    const int q0 = qblk * 64 + wid * 16;

    __shared__ __align__(16) ushort Kb[2][64 * 32];    // [key][32d] 64B rows, swizzled
    __shared__ __align__(16) ushort Vs[2][2][64][16];  // [dhalf][key][16d] 32B rows
    __shared__ __align__(16) ushort Pl[4][16][40];     // per-wave [q][key]
    __shared__ __align__(16) float  sbias[SS];

    const ushort* base  = qkv + (size_t)b * SS * 768;
    const ushort* kbase = base + DMODEL + h * HDIM;
    const ushort* vbase = base + 2 * DMODEL + h * HDIM;

    {   // mask bias
        const int i = tid * 4;
        const int4 mv = *reinterpret_cast<const int4*>(mask + b * SS + i);
        float4 bv;
        bv.x = mv.x ? 0.f : -3.4e38f;
        bv.y = mv.y ? 0.f : -3.4e38f;
        bv.z = mv.z ? 0.f : -3.4e38f;
        bv.w = mv.w ? 0.f : -3.4e38f;
        *reinterpret_cast<float4*>(&sbias[i]) = bv;
    }

    const bf16x8 qfrag = *(const bf16x8*)(
        base + (size_t)(q0 + c) * 768 + h * HDIM + g * 8);

    // staging assignments (byte offset o16 = tid*16 into each 4KB buffer)
    const int o16  = tid * 16;
    const int krow = o16 >> 6;                              // key (64B rows)
    const int kin  = (o16 & 63) ^ ((krow & 3) << 4);        // swizzled inner
    const int vhalf = o16 >> 11;                            // d half (0/1)
    const int vkey  = (o16 & 2047) >> 5;                    // key (32B rows)
    const int vd    = (vhalf << 4) + (((o16 >> 4) & 1) << 3);

    // ---- prologue: stage chunk 0
    async_ld16(kbase + (size_t)krow * 768 + (kin >> 1), (char*)&Kb[0][0] + o16);
    async_ld16(vbase + (size_t)vkey * 768 + vd, (char*)&Vs[0][0][0][0] + o16);
    __syncthreads();

    float m = -1e30f, lsum = 0.f;
    f32x4 o0 = {0.f, 0.f, 0.f, 0.f}, o1 = {0.f, 0.f, 0.f, 0.f};
    const f32x4 zf = {0.f, 0.f, 0.f, 0.f};

    for (int t = 0; t < 16; ++t) {
        const int cur = t & 1;
        if (t < 15) {   // stage chunk t+1 into the other buffer
            const int koff = (t + 1) * 64;
            async_ld16(kbase + (size_t)(koff + krow) * 768 + (kin >> 1),
                       (char*)&Kb[cur ^ 1][0] + o16);
            async_ld16(vbase + (size_t)(koff + vkey) * 768 + vd,
                       (char*)&Vs[cur ^ 1][0][0][0] + o16);
        }

        // ---- S^T tiles: rows = keys (4/lane), cols = q (=c)
        f32x4 s[4];
        #pragma unroll
        for (int kt = 0; kt < 4; ++kt) {
            const int row = kt * 16 + c;
            const bf16x8 kf = *(const bf16x8*)((const char*)&Kb[cur][0]
                + row * 64 + ((g * 16) ^ ((c & 3) << 4)));
            s[kt] = __builtin_amdgcn_mfma_f32_16x16x32_bf16(kf, qfrag, zf, 0, 0, 0);
        }
        #pragma unroll
        for (int kt = 0; kt < 4; ++kt) {
            const f32x4 bv = *reinterpret_cast<const f32x4*>(
                &sbias[t * 64 + kt * 16 + g * 4]);
            #pragma unroll
            for (int r = 0; r < 4; ++r) s[kt][r] += bv[r];
        }

        // ---- online softmax (per-lane state, q = c)
        float mx = fmaxf(fmaxf(s[0][0], s[0][1]), fmaxf(s[0][2], s[0][3]));
        #pragma unroll
        for (int kt = 1; kt < 4; ++kt)
            mx = fmaxf(mx, fmaxf(fmaxf(s[kt][0], s[kt][1]),
                                 fmaxf(s[kt][2], s[kt][3])));
        mx = fmaxf(mx, __shfl_xor(mx, 16));
        mx = fmaxf(mx, __shfl_xor(mx, 32));
        const float mn = fmaxf(m, mx);
        const float sc = __expf(m - mn);
        m = mn;

        float ls = 0.f;
        #pragma unroll
        for (int kt = 0; kt < 4; ++kt) {
            const float p0 = __expf(s[kt][0] - mn);
            const float p1 = __expf(s[kt][1] - mn);
            const float p2 = __expf(s[kt][2] - mn);
            const float p3 = __expf(s[kt][3] - mn);
            ls += (p0 + p1) + (p2 + p3);
            uint2 pk2 = make_uint2(pack2(p0, p1), pack2(p2, p3));
            *reinterpret_cast<uint2*>(&Pl[wid][c][kt * 16 + g * 4]) = pk2;
        }
        ls += __shfl_xor(ls, 16);
        ls += __shfl_xor(ls, 32);
        lsum = lsum * sc + ls;

        // ---- rescale O (rows q = g*4+r; scale lives at lane q=c)
        float scr[4];
        #pragma unroll
        for (int r = 0; r < 4; ++r) scr[r] = __shfl(sc, g * 4 + r);
        #pragma unroll
        for (int r = 0; r < 4; ++r) { o0[r] *= scr[r]; o1[r] *= scr[r]; }

        // ---- PV: O[16q][32d] += P[16q][64k] @ V[64k][32d] via tr16 B-frags
        #pragma unroll
        for (int ks = 0; ks < 2; ++ks) {
            const int vr0 = ks * 32 + g * 8;
            union UU { s16x4 h[2]; bf16x8 v; } u0, u1;
            u0.h[0] = tr16(&Vs[cur][0][vr0][c]);
            u0.h[1] = tr16(&Vs[cur][0][vr0 + 4][c]);
            u1.h[0] = tr16(&Vs[cur][1][vr0][c]);
            u1.h[1] = tr16(&Vs[cur][1][vr0 + 4][c]);
            tr_fence();
            const bf16x8 pa = *(const bf16x8*)&Pl[wid][c][ks * 32 + g * 8];
            o0 = __builtin_amdgcn_mfma_f32_16x16x32_bf16(pa, u0.v, o0, 0, 0, 0);
            o1 = __builtin_amdgcn_mfma_f32_16x16x32_bf16(pa, u1.v, o1, 0, 0, 0);
        }
        __syncthreads();
    }

    // ---- finalize
    const float rs = 1.f / lsum;
    float inv[4];
    #pragma unroll
    for (int r = 0; r < 4; ++r) inv[r] = __shfl(rs, g * 4 + r);
    #pragma unroll
    for (int r = 0; r < 4; ++r) {
        ushort* op = out + (size_t)(b * SS + q0 + g * 4 + r) * DMODEL + h * HDIM;
        op[c]      = f2bf(o0[r] * inv[r]);
        op[16 + c] = f2bf(o1[r] * inv[r]);
    }
}

// ---------------------------------------------------------------------------
// x = LayerNorm(a + x) * g + beta; also writes bf16 mirror xb. (LN2)
// ---------------------------------------------------------------------------
__global__ __launch_bounds__(256)
void add_ln_kernel(const float* __restrict__ a, const float* __restrict__ r,
                   const float* __restrict__ g, const float* __restrict__ beta,
                   float* __restrict__ out, ushort* __restrict__ xb)
{
    const int wave = threadIdx.x >> 6;
    const int lane = threadIdx.x & 63;
    const int row = blockIdx.x * 4 + wave;
    const size_t off = (size_t)row * DMODEL + lane * 4;

    const float4 va = *reinterpret_cast<const float4*>(a + off);
    const float4 vr = *reinterpret_cast<const float4*>(r + off);
    float v[4] = { va.x + vr.x, va.y + vr.y, va.z + vr.z, va.w + vr.w };

    float s = v[0] + v[1] + v[2] + v[3];
    #pragma unroll
    for (int o = 32; o >= 1; o >>= 1) s += __shfl_xor(s, o);
    const float mean = s * (1.f / DMODEL);

    float d0 = v[0] - mean, d1 = v[1] - mean, d2 = v[2] - mean, d3 = v[3] - mean;
    float sq = d0 * d0 + d1 * d1 + d2 * d2 + d3 * d3;
    #pragma unroll
    for (int o = 32; o >= 1; o >>= 1) sq += __shfl_xor(sq, o);
    const float inv = rsqrtf(sq * (1.f / DMODEL) + LN_EPS);

    const float4 vg = *reinterpret_cast<const float4*>(g + lane * 4);
    const float4 vb = *reinterpret_cast<const float4*>(beta + lane * 4);
    float4 o4;
    o4.x = d0 * inv * vg.x + vb.x;
    o4.y = d1 * inv * vg.y + vb.y;
    o4.z = d2 * inv * vg.z + vb.z;
    o4.w = d3 * inv * vg.w + vb.w;
    *reinterpret_cast<float4*>(out + off) = o4;
    *reinterpret_cast<uint2*>(xb + off) =
        make_uint2(pack2(o4.x, o4.y), pack2(o4.z, o4.w));
}

// ---------------------------------------------------------------------------
extern "C" void kernel_launch(void* const* d_in, const int* in_sizes, int n_in,
                              void* d_out, int out_size, void* d_ws, size_t ws_size,
                              hipStream_t stream)
{
    const float* x_in   = (const float*)d_in[0];
    const int*   maskp  = (const int*)d_in[1];
    const float* qkv_w  = (const float*)d_in[2];
    const float* qkv_b  = (const float*)d_in[3];
    const float* fc_w   = (const float*)d_in[4];
    const float* fc_b   = (const float*)d_in[5];
    const float* ln1_g  = (const float*)d_in[6];
    const float* ln1_b  = (const float*)d_in[7];
    const float* ln2_g  = (const float*)d_in[8];
    const float* ln2_b  = (const float*)d_in[9];
    const float* ff1_w  = (const float*)d_in[10];
    const float* ff1_b  = (const float*)d_in[11];
    const float* ff2_w  = (const float*)d_in[12];
    const float* ff2_b  = (const float*)d_in[13];

    float* x = (float*)d_out;                       // [4096,256] fp32 residual

    ushort* wt_qkv = (ushort*)d_ws;                 // [L][768][256]
    ushort* wt_fc  = wt_qkv + (size_t)NL * 768 * 256;
    ushort* wt_ff1 = wt_fc  + (size_t)NL * 256 * 256;
    ushort* wt_ff2 = wt_ff1 + (size_t)NL * 1024 * 256;
    ushort* big    = wt_ff2 + (size_t)NL * 256 * 1024;  // qkv_bf / h_bf (8MB)
    ushort* attn_bf= big + (size_t)MROWS * FFDIM;
    ushort* x_bf   = attn_bf + (size_t)MROWS * DMODEL;
    float*  o2     = (float*)(x_bf + (size_t)MROWS * DMODEL);

    wconv_all<<<dim3(768, 1, NL), 256, 0, stream>>>(
        qkv_w, fc_w, ff1_w, ff2_w, wt_qkv, wt_fc, wt_ff1, wt_ff2);
    convert_x<<<dim3(MROWS * DMODEL / 1024), 256, 0, stream>>>(x_in, x, x_bf);

    for (int l = 0; l < NL; ++l) {
        // qkv (bf16 out) [4096,768]
        gemm_mfma<64, 128, 2, 2, 0, 1><<<dim3(6, 64), 256, 0, stream>>>(
            x_bf, wt_qkv + (size_t)l * 768 * 256, qkv_b + l * 768,
            nullptr, big, 768, 256);
        // attention -> attn_bf [4096,256] bf16
        attn_mfma4<<<dim3(512), 256, 0, stream>>>(big, maskp, attn_bf);
        // x = LN1(attn @ fc_w + b + x)   (fused, 256 blocks)
        fc_ln<<<dim3(256), 256, 0, stream>>>(
            attn_bf, wt_fc + (size_t)l * 256 * 256, fc_b + l * 256,
            ln1_g + l * DMODEL, ln1_b + l * DMODEL, x, x_bf);
        // h = relu(x @ ff1_w + b) (bf16 out) [4096,1024]
        gemm_mfma<128, 128, 2, 2, 1, 1><<<dim3(8, 32), 256, 0, stream>>>(
            x_bf, wt_ff1 + (size_t)l * 1024 * 256, ff1_b + l * FFDIM,
            nullptr, big, 1024, 256);
        // o2 = h @ ff2_w + b (fp32 out)
        gemm_mfma<64, 64, 2, 2, 0, 0><<<dim3(4, 64), 256, 0, stream>>>(
            big, wt_ff2 + (size_t)l * 256 * 1024, ff2_b + l * DMODEL,
            o2, nullptr, 256, 1024);
        // x = LN2(x + o2)
        add_ln_kernel<<<dim3(MROWS / 4), 256, 0, stream>>>(
            o2, x, ln2_g + l * DMODEL, ln2_b + l * DMODEL, x, x_bf);
    }
}

// Round 7
// 296.176 us; speedup vs baseline: 1.0810x; 1.0086x over previous
//
#include <hip/hip_runtime.h>
#include <hip/hip_bf16.h>
#include <math.h>

#define NL 4
#define DMODEL 256
#define NH 8
#define FFDIM 1024
#define BB 4
#define SS 1024
#define HDIM 32
#define MROWS (BB * SS)   // 4096
#define LN_EPS 1e-5f

typedef __bf16 bf16x8 __attribute__((ext_vector_type(8)));
typedef float f32x4 __attribute__((ext_vector_type(4)));
typedef short s16x4 __attribute__((ext_vector_type(4)));
typedef unsigned int u32;

__device__ __forceinline__ ushort f2bf(float f) {
    uint u = __builtin_bit_cast(uint, f);
    u += 0x7fff + ((u >> 16) & 1);          // round-to-nearest-even
    return (ushort)(u >> 16);
}
__device__ __forceinline__ uint pack2(float a, float b) {
    return (uint)f2bf(a) | ((uint)f2bf(b) << 16);
}

// async global->LDS, 16B per lane (wave-uniform LDS base + lane*16 layout)
__device__ __forceinline__ void async_ld16(const void* g, void* l) {
    __builtin_amdgcn_global_load_lds(
        (const __attribute__((address_space(1))) u32*)g,
        (__attribute__((address_space(3))) u32*)l, 16, 0, 0);
}

// ds_read_b64_tr_b16: per-lane byte addr A -> 4 bf16 at A, A+32B, A+64B, A+96B
#if __has_builtin(__builtin_amdgcn_ds_read_tr16_b64)
#define TR_BUILTIN 1
#else
#define TR_BUILTIN 0
#endif

__device__ __forceinline__ s16x4 tr16(const ushort* p) {
    __attribute__((address_space(3))) s16x4* ap =
        (__attribute__((address_space(3))) s16x4*)p;
#if TR_BUILTIN
    return __builtin_amdgcn_ds_read_tr16_b64(ap);
#else
    s16x4 r;
    asm volatile("ds_read_b64_tr_b16 %0, %1" : "=v"(r) : "v"(ap) : "memory");
    return r;
#endif
}
__device__ __forceinline__ void tr_fence() {
#if !TR_BUILTIN
    asm volatile("s_waitcnt lgkmcnt(0)" ::: "memory");
    __builtin_amdgcn_sched_barrier(0);
#endif
}

// ---------------------------------------------------------------------------
// All weight transposes in one dispatch. Flat tile id -> {weight, tile}.
// ---------------------------------------------------------------------------
__global__ __launch_bounds__(256)
void wconv_all(const float* __restrict__ qkv_w, const float* __restrict__ fc_w,
               const float* __restrict__ ff1_w, const float* __restrict__ ff2_w,
               ushort* __restrict__ wq, ushort* __restrict__ wfc,
               ushort* __restrict__ wf1, ushort* __restrict__ wf2)
{
    const int l = blockIdx.z;
    int t = blockIdx.x;
    const float* src; ushort* dst; int K, N, nx;
    if (t < 192)      {          src = qkv_w; dst = wq;  K = 256;  N = 768;  nx = 24; }
    else if (t < 256) { t -= 192; src = fc_w;  dst = wfc; K = 256;  N = 256;  nx = 8; }
    else if (t < 512) { t -= 256; src = ff1_w; dst = wf1; K = 256;  N = 1024; nx = 32; }
    else              { t -= 512; src = ff2_w; dst = wf2; K = 1024; N = 256;  nx = 8; }
    src += (size_t)l * K * N;
    dst += (size_t)l * K * N;
    const int n0 = (t % nx) * 32, k0 = (t / nx) * 32;

    __shared__ ushort tt[32][33];
    const int tn = threadIdx.x & 31, tk8 = threadIdx.x >> 5;
    #pragma unroll
    for (int i = 0; i < 4; ++i)
        tt[tn][tk8 + i * 8] = f2bf(src[(size_t)(k0 + tk8 + i * 8) * N + n0 + tn]);
    __syncthreads();
    #pragma unroll
    for (int i = 0; i < 4; ++i)
        dst[(size_t)(n0 + tk8 + i * 8) * K + k0 + tn] = tt[tk8 + i * 8][tn];
}

// ---------------------------------------------------------------------------
// x_in fp32 -> x fp32 (d_out residual stream) + x_bf bf16 mirror
// ---------------------------------------------------------------------------
__global__ __launch_bounds__(256)
void convert_x(const float* __restrict__ xin, float* __restrict__ x,
               ushort* __restrict__ xb)
{
    const size_t i = ((size_t)blockIdx.x * 256 + threadIdx.x) * 4;
    const float4 v = *reinterpret_cast<const float4*>(xin + i);
    *reinterpret_cast<float4*>(x + i) = v;
    uint2 p = make_uint2(pack2(v.x, v.y), pack2(v.z, v.w));
    *reinterpret_cast<uint2*>(xb + i) = p;
}

// ---------------------------------------------------------------------------
// MFMA GEMM: C[M,N] = A[M,K](bf16) @ WT[N,K](bf16)^T + bias, opt ReLU.
// (round-4 verified structure; used for qkv and ff1)
// ---------------------------------------------------------------------------
template<int BM, int BN, int WM, int WN, int ACT, int OBF>
__global__ __launch_bounds__(256)
void gemm_mfma(const ushort* __restrict__ A, const ushort* __restrict__ WT,
               const float* __restrict__ bias, float* __restrict__ Cf,
               ushort* __restrict__ Cb, int N, int K)
{
    constexpr int BK = 64;
    constexpr int WR = BM / WM;
    constexpr int WC = BN / WN;
    constexpr int MR = WR / 16, NR = WC / 16;
    __shared__ __align__(16) ushort As[BM * BK];
    __shared__ __align__(16) ushort Bs[BN * BK];

    const int tid = threadIdx.x;
    const int m0 = blockIdx.y * BM, n0 = blockIdx.x * BN;
    const int wid = tid >> 6, lane = tid & 63;
    const int g = lane >> 4, c = lane & 15;
    const int wr = wid / WN, wc = wid % WN;

    f32x4 acc[MR][NR] = {};

    for (int k0 = 0; k0 < K; k0 += BK) {
        #pragma unroll
        for (int it = 0; it < (BM * BK * 2) / 4096; ++it) {
            const int o = tid * 16 + it * 4096;
            const int r = o >> 7, cb = o & 127;
            async_ld16(A + (size_t)(m0 + r) * K + k0 + (cb >> 1), (char*)As + o);
        }
        #pragma unroll
        for (int it = 0; it < (BN * BK * 2) / 4096; ++it) {
            const int o = tid * 16 + it * 4096;
            const int r = o >> 7, cb = o & 127;
            async_ld16(WT + (size_t)(n0 + r) * K + k0 + (cb >> 1), (char*)Bs + o);
        }
        __syncthreads();

        #pragma unroll
        for (int ks = 0; ks < 2; ++ks) {
            bf16x8 af[MR], bfr[NR];
            #pragma unroll
            for (int mi = 0; mi < MR; ++mi)
                af[mi] = *(const bf16x8*)&As[(wr * WR + mi * 16 + c) * BK + ks * 32 + g * 8];
            #pragma unroll
            for (int ni = 0; ni < NR; ++ni)
                bfr[ni] = *(const bf16x8*)&Bs[(wc * WC + ni * 16 + c) * BK + ks * 32 + g * 8];
            #pragma unroll
            for (int mi = 0; mi < MR; ++mi)
                #pragma unroll
                for (int ni = 0; ni < NR; ++ni)
                    acc[mi][ni] = __builtin_amdgcn_mfma_f32_16x16x32_bf16(
                        af[mi], bfr[ni], acc[mi][ni], 0, 0, 0);
        }
        __syncthreads();
    }

    float bv[NR];
    #pragma unroll
    for (int ni = 0; ni < NR; ++ni)
        bv[ni] = bias[n0 + wc * WC + ni * 16 + c];

    #pragma unroll
    for (int mi = 0; mi < MR; ++mi) {
        #pragma unroll
        for (int j = 0; j < 4; ++j) {
            const int row = m0 + wr * WR + mi * 16 + g * 4 + j;
            #pragma unroll
            for (int ni = 0; ni < NR; ++ni) {
                float v = acc[mi][ni][j] + bv[ni];
                if (ACT) v = fmaxf(v, 0.f);
                const int col = n0 + wc * WC + ni * 16 + c;
                if (OBF) Cb[(size_t)row * N + col] = f2bf(v);
                else     Cf[(size_t)row * N + col] = v;
            }
        }
    }
}

// ---------------------------------------------------------------------------
// Fused full-row GEMM + residual + LayerNorm.  BM=16 x N=256, 256 blocks x
// 256 threads (4 waves, 1x4).  Templated K (fc: 256, ff2: 1024).
// x = LN(A @ WT^T + bias + x); writes x (fp32) and x_bf (bf16).
// ---------------------------------------------------------------------------
template<int K>
__global__ __launch_bounds__(256)
void rowgemm_ln(const ushort* __restrict__ A, const ushort* __restrict__ WT,
                const float* __restrict__ bias, const float* __restrict__ lg,
                const float* __restrict__ lb, float* __restrict__ x,
                ushort* __restrict__ xb)
{
    constexpr int BK = 64, N = 256;
    __shared__ __align__(16) ushort As[16 * BK];
    __shared__ __align__(16) ushort Bs[N * BK];
    __shared__ float rsum[4][16], rsq[4][16], mval[16], ival[16];

    const int tid = threadIdx.x;
    const int m0 = blockIdx.x * 16;
    const int wid = tid >> 6, lane = tid & 63;
    const int g = lane >> 4, c = lane & 15;

    f32x4 acc[4] = {};

    for (int k0 = 0; k0 < K; k0 += BK) {
        if (tid < 128) {   // A: 2KB
            const int o = tid * 16;
            async_ld16(A + (size_t)(m0 + (o >> 7)) * K + k0 + ((o & 127) >> 1),
                       (char*)As + o);
        }
        #pragma unroll
        for (int it = 0; it < 8; ++it) {   // B: 32KB
            const int o = tid * 16 + it * 4096;
            async_ld16(WT + (size_t)(o >> 7) * K + k0 + ((o & 127) >> 1),
                       (char*)Bs + o);
        }
        __syncthreads();

        #pragma unroll
        for (int ks = 0; ks < 2; ++ks) {
            const bf16x8 af = *(const bf16x8*)&As[c * BK + ks * 32 + g * 8];
            #pragma unroll
            for (int ni = 0; ni < 4; ++ni) {
                const bf16x8 bf = *(const bf16x8*)&Bs[(wid * 64 + ni * 16 + c) * BK + ks * 32 + g * 8];
                acc[ni] = __builtin_amdgcn_mfma_f32_16x16x32_bf16(af, bf, acc[ni], 0, 0, 0);
            }
        }
        __syncthreads();
    }

    float bv[4], glv[4], blv[4];
    #pragma unroll
    for (int ni = 0; ni < 4; ++ni) {
        const int col = wid * 64 + ni * 16 + c;
        bv[ni] = bias[col]; glv[ni] = lg[col]; blv[ni] = lb[col];
    }

    #pragma unroll
    for (int j = 0; j < 4; ++j) {
        const int row = g * 4 + j;
        float s = 0.f, q = 0.f;
        #pragma unroll
        for (int ni = 0; ni < 4; ++ni) {
            const int col = wid * 64 + ni * 16 + c;
            float vv = acc[ni][j] + bv[ni] + x[(size_t)(m0 + row) * N + col];
            acc[ni][j] = vv;
            s += vv; q += vv * vv;
        }
        #pragma unroll
        for (int off = 1; off < 16; off <<= 1) {
            s += __shfl_xor(s, off);
            q += __shfl_xor(q, off);
        }
        if (c == 0) { rsum[wid][row] = s; rsq[wid][row] = q; }
    }
    __syncthreads();
    if (tid < 16) {
        const float s = rsum[0][tid] + rsum[1][tid] + rsum[2][tid] + rsum[3][tid];
        const float q = rsq[0][tid] + rsq[1][tid] + rsq[2][tid] + rsq[3][tid];
        const float mean = s * (1.f / N);
        const float var = q * (1.f / N) - mean * mean;
        mval[tid] = mean;
        ival[tid] = rsqrtf(var + LN_EPS);
    }
    __syncthreads();
    #pragma unroll
    for (int j = 0; j < 4; ++j) {
        const int row = g * 4 + j;
        const float mean = mval[row], inv = ival[row];
        #pragma unroll
        for (int ni = 0; ni < 4; ++ni) {
            const int col = wid * 64 + ni * 16 + c;
            const float y = (acc[ni][j] - mean) * inv * glv[ni] + blv[ni];
            x[(size_t)(m0 + row) * N + col] = y;
            xb[(size_t)(m0 + row) * N + col] = f2bf(y);
        }
    }
}

// ---------------------------------------------------------------------------
// Flash attention v5: 4 waves/block, QBLK=64, KVBLK=128 double-buffered,
// 512 blocks (2/CU).  K staged async with 16B XOR swizzle; V staged async
// linear [dhalf][key][16] and read via ds_read_b64_tr_b16.  Swapped QK^T,
// per-lane scalar softmax state (q = lane&15).
// FIX vs r4-r6: Pl rows sized for full 128-key chunk (was 40 < 64: flat
// overflow spilled wave 3's P into sbias -> scheduling-dependent corruption).
// ---------------------------------------------------------------------------
__global__ __launch_bounds__(256)
void attn_mfma5(const ushort* __restrict__ qkv, const int* __restrict__ mask,
                ushort* __restrict__ out)
{
    const int tid = threadIdx.x;
    const int lane = tid & 63, wid = tid >> 6;
    const int g = lane >> 4, c = lane & 15;
    const int qblk = blockIdx.x & 15;          // 16 q-blocks of 64
    const int bh = blockIdx.x >> 4;            // 0..31
    const int h = bh & (NH - 1), b = bh >> 3;
    const int q0 = qblk * 64 + wid * 16;

    __shared__ __align__(16) ushort Kb[2][128 * 32];    // 16KB [key][32d] 64B rows, swz
    __shared__ __align__(16) ushort Vs[2][2][128][16];  // 16KB [dhalf][key][16d]
    __shared__ __align__(16) ushort Pl[4][16][136];     // per-wave [q][0..127 key]+pad
    __shared__ __align__(16) float  sbias[SS];

    const ushort* base  = qkv + (size_t)b * SS * 768;
    const ushort* kbase = base + DMODEL + h * HDIM;
    const ushort* vbase = base + 2 * DMODEL + h * HDIM;

    {   // mask bias
        const int i = tid * 4;
        const int4 mv = *reinterpret_cast<const int4*>(mask + b * SS + i);
        float4 bv;
        bv.x = mv.x ? 0.f : -3.4e38f;
        bv.y = mv.y ? 0.f : -3.4e38f;
        bv.z = mv.z ? 0.f : -3.4e38f;
        bv.w = mv.w ? 0.f : -3.4e38f;
        *reinterpret_cast<float4*>(&sbias[i]) = bv;
    }

    const bf16x8 qfrag = *(const bf16x8*)(
        base + (size_t)(q0 + c) * 768 + h * HDIM + g * 8);

    // staging assignments (o16 = tid*16 byte offset; each async covers 4KB)
    const int o16  = tid * 16;
    const int krow = o16 >> 6;                              // key 0..63 (64B rows)
    const int kin  = (o16 & 63) ^ ((krow & 3) << 4);        // swizzled inner bytes
    const int vkey = o16 >> 5;                              // key 0..127 (32B rows)
    const int vd8  = ((o16 >> 4) & 1) << 3;                 // d sub-offset 0/8

    #define STAGE(buf, koff)                                                     \
        do {                                                                     \
            async_ld16(kbase + (size_t)((koff) + krow) * 768 + (kin >> 1),       \
                       (char*)&Kb[buf][0] + o16);                                \
            async_ld16(kbase + (size_t)((koff) + 64 + krow) * 768 + (kin >> 1),  \
                       (char*)&Kb[buf][0] + o16 + 4096);                         \
            async_ld16(vbase + (size_t)((koff) + vkey) * 768 + vd8,              \
                       (char*)&Vs[buf][0][0][0] + o16);                          \
            async_ld16(vbase + (size_t)((koff) + vkey) * 768 + 16 + vd8,         \
                       (char*)&Vs[buf][0][0][0] + o16 + 4096);                   \
        } while (0)

    STAGE(0, 0);
    __syncthreads();

    float m = -1e30f, lsum = 0.f;
    f32x4 o0 = {0.f, 0.f, 0.f, 0.f}, o1 = {0.f, 0.f, 0.f, 0.f};
    const f32x4 zf = {0.f, 0.f, 0.f, 0.f};

    for (int t = 0; t < 8; ++t) {
        const int cur = t & 1;
        if (t < 7) STAGE(cur ^ 1, (t + 1) * 128);

        // ---- S^T tiles: rows = keys (4/lane), cols = q (=c)
        f32x4 s[8];
        #pragma unroll
        for (int kt = 0; kt < 8; ++kt) {
            const int row = kt * 16 + c;
            const bf16x8 kf = *(const bf16x8*)((const char*)&Kb[cur][0]
                + row * 64 + ((g * 16) ^ ((c & 3) << 4)));
            s[kt] = __builtin_amdgcn_mfma_f32_16x16x32_bf16(kf, qfrag, zf, 0, 0, 0);
        }
        #pragma unroll
        for (int kt = 0; kt < 8; ++kt) {
            const f32x4 bv = *reinterpret_cast<const f32x4*>(
                &sbias[t * 128 + kt * 16 + g * 4]);
            #pragma unroll
            for (int r = 0; r < 4; ++r) s[kt][r] += bv[r];
        }

        // ---- online softmax (per-lane state, q = c)
        float mx = fmaxf(fmaxf(s[0][0], s[0][1]), fmaxf(s[0][2], s[0][3]));
        #pragma unroll
        for (int kt = 1; kt < 8; ++kt)
            mx = fmaxf(mx, fmaxf(fmaxf(s[kt][0], s[kt][1]),
                                 fmaxf(s[kt][2], s[kt][3])));
        mx = fmaxf(mx, __shfl_xor(mx, 16));
        mx = fmaxf(mx, __shfl_xor(mx, 32));
        const float mn = fmaxf(m, mx);
        const float sc = __expf(m - mn);
        m = mn;

        float ls = 0.f;
        #pragma unroll
        for (int kt = 0; kt < 8; ++kt) {
            const float p0 = __expf(s[kt][0] - mn);
            const float p1 = __expf(s[kt][1] - mn);
            const float p2 = __expf(s[kt][2] - mn);
            const float p3 = __expf(s[kt][3] - mn);
            ls += (p0 + p1) + (p2 + p3);
            uint2 pk2 = make_uint2(pack2(p0, p1), pack2(p2, p3));
            *reinterpret_cast<uint2*>(&Pl[wid][c][kt * 16 + g * 4]) = pk2;
        }
        ls += __shfl_xor(ls, 16);
        ls += __shfl_xor(ls, 32);
        lsum = lsum * sc + ls;

        // ---- rescale O (rows q = g*4+r; scale lives at lane q=c)
        float scr[4];
        #pragma unroll
        for (int r = 0; r < 4; ++r) scr[r] = __shfl(sc, g * 4 + r);
        #pragma unroll
        for (int r = 0; r < 4; ++r) { o0[r] *= scr[r]; o1[r] *= scr[r]; }

        // ---- PV: O[16q][32d] += P[16q][128k] @ V[128k][32d]
        #pragma unroll
        for (int ks = 0; ks < 4; ++ks) {
            const int vr0 = ks * 32 + g * 8;
            union UU { s16x4 h[2]; bf16x8 v; } u0, u1;
            u0.h[0] = tr16(&Vs[cur][0][vr0][c]);
            u0.h[1] = tr16(&Vs[cur][0][vr0 + 4][c]);
            u1.h[0] = tr16(&Vs[cur][1][vr0][c]);
            u1.h[1] = tr16(&Vs[cur][1][vr0 + 4][c]);
            tr_fence();
            const bf16x8 pa = *(const bf16x8*)&Pl[wid][c][ks * 32 + g * 8];
            o0 = __builtin_amdgcn_mfma_f32_16x16x32_bf16(pa, u0.v, o0, 0, 0, 0);
            o1 = __builtin_amdgcn_mfma_f32_16x16x32_bf16(pa, u1.v, o1, 0, 0, 0);
        }
        __syncthreads();
    }
    #undef STAGE

    // ---- finalize
    const float rs = 1.f / lsum;
    float inv[4];
    #pragma unroll
    for (int r = 0; r < 4; ++r) inv[r] = __shfl(rs, g * 4 + r);
    #pragma unroll
    for (int r = 0; r < 4; ++r) {
        ushort* op = out + (size_t)(b * SS + q0 + g * 4 + r) * DMODEL + h * HDIM;
        op[c]      = f2bf(o0[r] * inv[r]);
        op[16 + c] = f2bf(o1[r] * inv[r]);
    }
}

// ---------------------------------------------------------------------------
extern "C" void kernel_launch(void* const* d_in, const int* in_sizes, int n_in,
                              void* d_out, int out_size, void* d_ws, size_t ws_size,
                              hipStream_t stream)
{
    const float* x_in   = (const float*)d_in[0];
    const int*   maskp  = (const int*)d_in[1];
    const float* qkv_w  = (const float*)d_in[2];
    const float* qkv_b  = (const float*)d_in[3];
    const float* fc_w   = (const float*)d_in[4];
    const float* fc_b   = (const float*)d_in[5];
    const float* ln1_g  = (const float*)d_in[6];
    const float* ln1_b  = (const float*)d_in[7];
    const float* ln2_g  = (const float*)d_in[8];
    const float* ln2_b  = (const float*)d_in[9];
    const float* ff1_w  = (const float*)d_in[10];
    const float* ff1_b  = (const float*)d_in[11];
    const float* ff2_w  = (const float*)d_in[12];
    const float* ff2_b  = (const float*)d_in[13];

    float* x = (float*)d_out;                       // [4096,256] fp32 residual

    ushort* wt_qkv = (ushort*)d_ws;                 // [L][768][256]
    ushort* wt_fc  = wt_qkv + (size_t)NL * 768 * 256;
    ushort* wt_ff1 = wt_fc  + (size_t)NL * 256 * 256;
    ushort* wt_ff2 = wt_ff1 + (size_t)NL * 1024 * 256;
    ushort* big    = wt_ff2 + (size_t)NL * 256 * 1024;  // qkv_bf / h_bf (8MB)
    ushort* attn_bf= big + (size_t)MROWS * FFDIM;
    ushort* x_bf   = attn_bf + (size_t)MROWS * DMODEL;

    wconv_all<<<dim3(768, 1, NL), 256, 0, stream>>>(
        qkv_w, fc_w, ff1_w, ff2_w, wt_qkv, wt_fc, wt_ff1, wt_ff2);
    convert_x<<<dim3(MROWS * DMODEL / 1024), 256, 0, stream>>>(x_in, x, x_bf);

    for (int l = 0; l < NL; ++l) {
        // qkv (bf16 out) [4096,768]
        gemm_mfma<64, 128, 2, 2, 0, 1><<<dim3(6, 64), 256, 0, stream>>>(
            x_bf, wt_qkv + (size_t)l * 768 * 256, qkv_b + l * 768,
            nullptr, big, 768, 256);
        // attention -> attn_bf [4096,256] bf16
        attn_mfma5<<<dim3(512), 256, 0, stream>>>(big, maskp, attn_bf);
        // x = LN1(attn @ fc_w + b + x)
        rowgemm_ln<256><<<dim3(256), 256, 0, stream>>>(
            attn_bf, wt_fc + (size_t)l * 256 * 256, fc_b + l * 256,
            ln1_g + l * DMODEL, ln1_b + l * DMODEL, x, x_bf);
        // h = relu(x @ ff1_w + b) (bf16 out) [4096,1024]
        gemm_mfma<128, 128, 2, 2, 1, 1><<<dim3(8, 32), 256, 0, stream>>>(
            x_bf, wt_ff1 + (size_t)l * 1024 * 256, ff1_b + l * FFDIM,
            nullptr, big, 1024, 256);
        // x = LN2(h @ ff2_w + b + x)
        rowgemm_ln<1024><<<dim3(256), 256, 0, stream>>>(
            big, wt_ff2 + (size_t)l * 256 * 1024, ff2_b + l * DMODEL,
            ln2_g + l * DMODEL, ln2_b + l * DMODEL, x, x_bf);
    }
}

// Round 8
// 294.416 us; speedup vs baseline: 1.0874x; 1.0060x over previous
//
#include <hip/hip_runtime.h>
#include <hip/hip_bf16.h>
#include <math.h>

#define NL 4
#define DMODEL 256
#define NH 8
#define FFDIM 1024
#define BB 4
#define SS 1024
#define HDIM 32
#define MROWS (BB * SS)   // 4096
#define LN_EPS 1e-5f

typedef __bf16 bf16x8 __attribute__((ext_vector_type(8)));
typedef float f32x4 __attribute__((ext_vector_type(4)));
typedef short s16x4 __attribute__((ext_vector_type(4)));
typedef unsigned int u32;

__device__ __forceinline__ ushort f2bf(float f) {
    uint u = __builtin_bit_cast(uint, f);
    u += 0x7fff + ((u >> 16) & 1);          // round-to-nearest-even
    return (ushort)(u >> 16);
}
__device__ __forceinline__ uint pack2(float a, float b) {
    return (uint)f2bf(a) | ((uint)f2bf(b) << 16);
}

// async global->LDS, 16B per lane (wave-uniform LDS base + lane*16 layout)
__device__ __forceinline__ void async_ld16(const void* g, void* l) {
    __builtin_amdgcn_global_load_lds(
        (const __attribute__((address_space(1))) u32*)g,
        (__attribute__((address_space(3))) u32*)l, 16, 0, 0);
}

// ds_read_b64_tr_b16: per-lane byte addr A -> 4 bf16 at A, A+32B, A+64B, A+96B
#if __has_builtin(__builtin_amdgcn_ds_read_tr16_b64)
#define TR_BUILTIN 1
#else
#define TR_BUILTIN 0
#endif

__device__ __forceinline__ s16x4 tr16(const ushort* p) {
    __attribute__((address_space(3))) s16x4* ap =
        (__attribute__((address_space(3))) s16x4*)p;
#if TR_BUILTIN
    return __builtin_amdgcn_ds_read_tr16_b64(ap);
#else
    s16x4 r;
    asm volatile("ds_read_b64_tr_b16 %0, %1" : "=v"(r) : "v"(ap) : "memory");
    return r;
#endif
}
__device__ __forceinline__ void tr_fence() {
#if !TR_BUILTIN
    asm volatile("s_waitcnt lgkmcnt(0)" ::: "memory");
    __builtin_amdgcn_sched_barrier(0);
#endif
}

// ---------------------------------------------------------------------------
// All weight transposes in one dispatch. Flat tile id -> {weight, tile}.
// ---------------------------------------------------------------------------
__global__ __launch_bounds__(256)
void wconv_all(const float* __restrict__ qkv_w, const float* __restrict__ fc_w,
               const float* __restrict__ ff1_w, const float* __restrict__ ff2_w,
               ushort* __restrict__ wq, ushort* __restrict__ wfc,
               ushort* __restrict__ wf1, ushort* __restrict__ wf2)
{
    const int l = blockIdx.z;
    int t = blockIdx.x;
    const float* src; ushort* dst; int K, N, nx;
    if (t < 192)      {          src = qkv_w; dst = wq;  K = 256;  N = 768;  nx = 24; }
    else if (t < 256) { t -= 192; src = fc_w;  dst = wfc; K = 256;  N = 256;  nx = 8; }
    else if (t < 512) { t -= 256; src = ff1_w; dst = wf1; K = 256;  N = 1024; nx = 32; }
    else              { t -= 512; src = ff2_w; dst = wf2; K = 1024; N = 256;  nx = 8; }
    src += (size_t)l * K * N;
    dst += (size_t)l * K * N;
    const int n0 = (t % nx) * 32, k0 = (t / nx) * 32;

    __shared__ ushort tt[32][33];
    const int tn = threadIdx.x & 31, tk8 = threadIdx.x >> 5;
    #pragma unroll
    for (int i = 0; i < 4; ++i)
        tt[tn][tk8 + i * 8] = f2bf(src[(size_t)(k0 + tk8 + i * 8) * N + n0 + tn]);
    __syncthreads();
    #pragma unroll
    for (int i = 0; i < 4; ++i)
        dst[(size_t)(n0 + tk8 + i * 8) * K + k0 + tn] = tt[tk8 + i * 8][tn];
}

// ---------------------------------------------------------------------------
// x_in fp32 -> x fp32 (d_out residual stream) + x_bf bf16 mirror
// ---------------------------------------------------------------------------
__global__ __launch_bounds__(256)
void convert_x(const float* __restrict__ xin, float* __restrict__ x,
               ushort* __restrict__ xb)
{
    const size_t i = ((size_t)blockIdx.x * 256 + threadIdx.x) * 4;
    const float4 v = *reinterpret_cast<const float4*>(xin + i);
    *reinterpret_cast<float4*>(x + i) = v;
    uint2 p = make_uint2(pack2(v.x, v.y), pack2(v.z, v.w));
    *reinterpret_cast<uint2*>(xb + i) = p;
}

// ---------------------------------------------------------------------------
// MFMA GEMM: C[M,N] = A[M,K](bf16) @ WT[N,K](bf16)^T + bias, opt ReLU.
// (round-4 verified structure; used for qkv and ff1)
// ---------------------------------------------------------------------------
template<int BM, int BN, int WM, int WN, int ACT, int OBF>
__global__ __launch_bounds__(256)
void gemm_mfma(const ushort* __restrict__ A, const ushort* __restrict__ WT,
               const float* __restrict__ bias, float* __restrict__ Cf,
               ushort* __restrict__ Cb, int N, int K)
{
    constexpr int BK = 64;
    constexpr int WR = BM / WM;
    constexpr int WC = BN / WN;
    constexpr int MR = WR / 16, NR = WC / 16;
    __shared__ __align__(16) ushort As[BM * BK];
    __shared__ __align__(16) ushort Bs[BN * BK];

    const int tid = threadIdx.x;
    const int m0 = blockIdx.y * BM, n0 = blockIdx.x * BN;
    const int wid = tid >> 6, lane = tid & 63;
    const int g = lane >> 4, c = lane & 15;
    const int wr = wid / WN, wc = wid % WN;

    f32x4 acc[MR][NR] = {};

    for (int k0 = 0; k0 < K; k0 += BK) {
        #pragma unroll
        for (int it = 0; it < (BM * BK * 2) / 4096; ++it) {
            const int o = tid * 16 + it * 4096;
            const int r = o >> 7, cb = o & 127;
            async_ld16(A + (size_t)(m0 + r) * K + k0 + (cb >> 1), (char*)As + o);
        }
        #pragma unroll
        for (int it = 0; it < (BN * BK * 2) / 4096; ++it) {
            const int o = tid * 16 + it * 4096;
            const int r = o >> 7, cb = o & 127;
            async_ld16(WT + (size_t)(n0 + r) * K + k0 + (cb >> 1), (char*)Bs + o);
        }
        __syncthreads();

        #pragma unroll
        for (int ks = 0; ks < 2; ++ks) {
            bf16x8 af[MR], bfr[NR];
            #pragma unroll
            for (int mi = 0; mi < MR; ++mi)
                af[mi] = *(const bf16x8*)&As[(wr * WR + mi * 16 + c) * BK + ks * 32 + g * 8];
            #pragma unroll
            for (int ni = 0; ni < NR; ++ni)
                bfr[ni] = *(const bf16x8*)&Bs[(wc * WC + ni * 16 + c) * BK + ks * 32 + g * 8];
            #pragma unroll
            for (int mi = 0; mi < MR; ++mi)
                #pragma unroll
                for (int ni = 0; ni < NR; ++ni)
                    acc[mi][ni] = __builtin_amdgcn_mfma_f32_16x16x32_bf16(
                        af[mi], bfr[ni], acc[mi][ni], 0, 0, 0);
        }
        __syncthreads();
    }

    float bv[NR];
    #pragma unroll
    for (int ni = 0; ni < NR; ++ni)
        bv[ni] = bias[n0 + wc * WC + ni * 16 + c];

    #pragma unroll
    for (int mi = 0; mi < MR; ++mi) {
        #pragma unroll
        for (int j = 0; j < 4; ++j) {
            const int row = m0 + wr * WR + mi * 16 + g * 4 + j;
            #pragma unroll
            for (int ni = 0; ni < NR; ++ni) {
                float v = acc[mi][ni][j] + bv[ni];
                if (ACT) v = fmaxf(v, 0.f);
                const int col = n0 + wc * WC + ni * 16 + c;
                if (OBF) Cb[(size_t)row * N + col] = f2bf(v);
                else     Cf[(size_t)row * N + col] = v;
            }
        }
    }
}

// ---------------------------------------------------------------------------
// Fused full-row GEMM + residual + LayerNorm (two-pass variance, matches ref).
// BM=16 x N=256, 256 blocks x 256 threads (4 waves, 1x4).  Templated K.
// ---------------------------------------------------------------------------
template<int K>
__global__ __launch_bounds__(256)
void rowgemm_ln(const ushort* __restrict__ A, const ushort* __restrict__ WT,
                const float* __restrict__ bias, const float* __restrict__ lg,
                const float* __restrict__ lb, float* __restrict__ x,
                ushort* __restrict__ xb)
{
    constexpr int BK = 64, N = 256;
    __shared__ __align__(16) ushort As[16 * BK];
    __shared__ __align__(16) ushort Bs[N * BK];
    __shared__ float rsum[4][16], rsq[4][16], mval[16], ival[16];

    const int tid = threadIdx.x;
    const int m0 = blockIdx.x * 16;
    const int wid = tid >> 6, lane = tid & 63;
    const int g = lane >> 4, c = lane & 15;

    f32x4 acc[4] = {};

    for (int k0 = 0; k0 < K; k0 += BK) {
        if (tid < 128) {   // A: 2KB
            const int o = tid * 16;
            async_ld16(A + (size_t)(m0 + (o >> 7)) * K + k0 + ((o & 127) >> 1),
                       (char*)As + o);
        }
        #pragma unroll
        for (int it = 0; it < 8; ++it) {   // B: 32KB
            const int o = tid * 16 + it * 4096;
            async_ld16(WT + (size_t)(o >> 7) * K + k0 + ((o & 127) >> 1),
                       (char*)Bs + o);
        }
        __syncthreads();

        #pragma unroll
        for (int ks = 0; ks < 2; ++ks) {
            const bf16x8 af = *(const bf16x8*)&As[c * BK + ks * 32 + g * 8];
            #pragma unroll
            for (int ni = 0; ni < 4; ++ni) {
                const bf16x8 bf = *(const bf16x8*)&Bs[(wid * 64 + ni * 16 + c) * BK + ks * 32 + g * 8];
                acc[ni] = __builtin_amdgcn_mfma_f32_16x16x32_bf16(af, bf, acc[ni], 0, 0, 0);
            }
        }
        __syncthreads();
    }

    float bv[4], glv[4], blv[4];
    #pragma unroll
    for (int ni = 0; ni < 4; ++ni) {
        const int col = wid * 64 + ni * 16 + c;
        bv[ni] = bias[col]; glv[ni] = lg[col]; blv[ni] = lb[col];
    }

    // pass 1: v = acc + bias + residual; row sums -> mean
    #pragma unroll
    for (int j = 0; j < 4; ++j) {
        const int row = g * 4 + j;
        float s = 0.f;
        #pragma unroll
        for (int ni = 0; ni < 4; ++ni) {
            const int col = wid * 64 + ni * 16 + c;
            float vv = acc[ni][j] + bv[ni] + x[(size_t)(m0 + row) * N + col];
            acc[ni][j] = vv;
            s += vv;
        }
        #pragma unroll
        for (int off = 1; off < 16; off <<= 1) s += __shfl_xor(s, off);
        if (c == 0) rsum[wid][row] = s;
    }
    __syncthreads();
    if (tid < 16)
        mval[tid] = (rsum[0][tid] + rsum[1][tid] + rsum[2][tid] + rsum[3][tid])
                    * (1.f / N);
    __syncthreads();

    // pass 2: variance of deviations (matches reference arithmetic)
    #pragma unroll
    for (int j = 0; j < 4; ++j) {
        const int row = g * 4 + j;
        const float mean = mval[row];
        float q = 0.f;
        #pragma unroll
        for (int ni = 0; ni < 4; ++ni) {
            const float d = acc[ni][j] - mean;
            q += d * d;
        }
        #pragma unroll
        for (int off = 1; off < 16; off <<= 1) q += __shfl_xor(q, off);
        if (c == 0) rsq[wid][row] = q;
    }
    __syncthreads();
    if (tid < 16) {
        const float q = rsq[0][tid] + rsq[1][tid] + rsq[2][tid] + rsq[3][tid];
        ival[tid] = rsqrtf(q * (1.f / N) + LN_EPS);
    }
    __syncthreads();

    #pragma unroll
    for (int j = 0; j < 4; ++j) {
        const int row = g * 4 + j;
        const float mean = mval[row], inv = ival[row];
        #pragma unroll
        for (int ni = 0; ni < 4; ++ni) {
            const int col = wid * 64 + ni * 16 + c;
            const float y = (acc[ni][j] - mean) * inv * glv[ni] + blv[ni];
            x[(size_t)(m0 + row) * N + col] = y;
            xb[(size_t)(m0 + row) * N + col] = f2bf(y);
        }
    }
}

// ---------------------------------------------------------------------------
// Flash attention v6: v5 structure (4 waves, QBLK=64, KVBLK=128 dbuf, swizzled
// K, tr16 V) + T13 defer-rescale (THR=8, per-lane partial-max test), T5
// setprio around MFMA clusters, per-lane partial lsum (one final reduce),
// Pl stride 144 (P-read bank conflict 8-way -> 4-way), mask-clean fast path.
// Defer-max is algebraically identical: scale factors cancel in O/lsum.
// ---------------------------------------------------------------------------
__global__ __launch_bounds__(256)
void attn_mfma6(const ushort* __restrict__ qkv, const int* __restrict__ mask,
                ushort* __restrict__ out)
{
    const int tid = threadIdx.x;
    const int lane = tid & 63, wid = tid >> 6;
    const int g = lane >> 4, c = lane & 15;
    const int qblk = blockIdx.x & 15;          // 16 q-blocks of 64
    const int bh = blockIdx.x >> 4;            // 0..31
    const int h = bh & (NH - 1), b = bh >> 3;
    const int q0 = qblk * 64 + wid * 16;

    __shared__ __align__(16) ushort Kb[2][128 * 32];    // [key][32d] 64B rows, swz
    __shared__ __align__(16) ushort Vs[2][2][128][16];  // [dhalf][key][16d]
    __shared__ __align__(16) ushort Pl[4][16][144];     // per-wave [q][key], 288B rows
    __shared__ __align__(16) float  sbias[SS];
    __shared__ int mflag[4];

    const ushort* base  = qkv + (size_t)b * SS * 768;
    const ushort* kbase = base + DMODEL + h * HDIM;
    const ushort* vbase = base + 2 * DMODEL + h * HDIM;

    {   // mask bias + per-wave "any masked" flag
        const int i = tid * 4;
        const int4 mv = *reinterpret_cast<const int4*>(mask + b * SS + i);
        float4 bv;
        bv.x = mv.x ? 0.f : -3.4e38f;
        bv.y = mv.y ? 0.f : -3.4e38f;
        bv.z = mv.z ? 0.f : -3.4e38f;
        bv.w = mv.w ? 0.f : -3.4e38f;
        *reinterpret_cast<float4*>(&sbias[i]) = bv;
        const int miss = __any(!(mv.x && mv.y && mv.z && mv.w));
        if (lane == 0) mflag[wid] = miss;
    }

    const bf16x8 qfrag = *(const bf16x8*)(
        base + (size_t)(q0 + c) * 768 + h * HDIM + g * 8);

    // staging assignments (o16 = tid*16 byte offset; each async covers 4KB)
    const int o16  = tid * 16;
    const int krow = o16 >> 6;                              // key 0..63 (64B rows)
    const int kin  = (o16 & 63) ^ ((krow & 3) << 4);        // swizzled inner bytes
    const int vkey = o16 >> 5;                              // key 0..127 (32B rows)
    const int vd8  = ((o16 >> 4) & 1) << 3;                 // d sub-offset 0/8

    #define STAGE(buf, koff)                                                     \
        do {                                                                     \
            async_ld16(kbase + (size_t)((koff) + krow) * 768 + (kin >> 1),       \
                       (char*)&Kb[buf][0] + o16);                                \
            async_ld16(kbase + (size_t)((koff) + 64 + krow) * 768 + (kin >> 1),  \
                       (char*)&Kb[buf][0] + o16 + 4096);                         \
            async_ld16(vbase + (size_t)((koff) + vkey) * 768 + vd8,              \
                       (char*)&Vs[buf][0][0][0] + o16);                          \
            async_ld16(vbase + (size_t)((koff) + vkey) * 768 + 16 + vd8,         \
                       (char*)&Vs[buf][0][0][0] + o16 + 4096);                   \
        } while (0)

    STAGE(0, 0);
    __syncthreads();
    const int anyMasked = mflag[0] | mflag[1] | mflag[2] | mflag[3];

    float m = -1e30f, lpart = 0.f;
    f32x4 o0 = {0.f, 0.f, 0.f, 0.f}, o1 = {0.f, 0.f, 0.f, 0.f};
    const f32x4 zf = {0.f, 0.f, 0.f, 0.f};

    for (int t = 0; t < 8; ++t) {
        const int cur = t & 1;
        if (t < 7) STAGE(cur ^ 1, (t + 1) * 128);

        // ---- S^T tiles: rows = keys (4/lane), cols = q (=c)
        f32x4 s[8];
        __builtin_amdgcn_s_setprio(1);
        #pragma unroll
        for (int kt = 0; kt < 8; ++kt) {
            const int row = kt * 16 + c;
            const bf16x8 kf = *(const bf16x8*)((const char*)&Kb[cur][0]
                + row * 64 + ((g * 16) ^ ((c & 3) << 4)));
            s[kt] = __builtin_amdgcn_mfma_f32_16x16x32_bf16(kf, qfrag, zf, 0, 0, 0);
        }
        __builtin_amdgcn_s_setprio(0);

        if (anyMasked) {
            #pragma unroll
            for (int kt = 0; kt < 8; ++kt) {
                const f32x4 bv = *reinterpret_cast<const f32x4*>(
                    &sbias[t * 128 + kt * 16 + g * 4]);
                #pragma unroll
                for (int r = 0; r < 4; ++r) s[kt][r] += bv[r];
            }
        }

        // ---- online softmax, defer-rescale (per-lane partial max test)
        float mx = fmaxf(fmaxf(s[0][0], s[0][1]), fmaxf(s[0][2], s[0][3]));
        #pragma unroll
        for (int kt = 1; kt < 8; ++kt)
            mx = fmaxf(mx, fmaxf(fmaxf(s[kt][0], s[kt][1]),
                                 fmaxf(s[kt][2], s[kt][3])));
        if (!__all(mx <= m + 8.f)) {
            float fm = fmaxf(mx, __shfl_xor(mx, 16));
            fm = fmaxf(fm, __shfl_xor(fm, 32));
            const float mn = fmaxf(m, fm);
            const float sc = __expf(m - mn);
            m = mn;
            lpart *= sc;
            float scr[4];
            #pragma unroll
            for (int r = 0; r < 4; ++r) scr[r] = __shfl(sc, g * 4 + r);
            #pragma unroll
            for (int r = 0; r < 4; ++r) { o0[r] *= scr[r]; o1[r] *= scr[r]; }
        }

        float ls = 0.f;
        #pragma unroll
        for (int kt = 0; kt < 8; ++kt) {
            const float p0 = __expf(s[kt][0] - m);
            const float p1 = __expf(s[kt][1] - m);
            const float p2 = __expf(s[kt][2] - m);
            const float p3 = __expf(s[kt][3] - m);
            ls += (p0 + p1) + (p2 + p3);
            uint2 pk2 = make_uint2(pack2(p0, p1), pack2(p2, p3));
            *reinterpret_cast<uint2*>(&Pl[wid][c][kt * 16 + g * 4]) = pk2;
        }
        lpart += ls;

        // ---- PV: O[16q][32d] += P[16q][128k] @ V[128k][32d]
        __builtin_amdgcn_s_setprio(1);
        #pragma unroll
        for (int ks = 0; ks < 4; ++ks) {
            const int vr0 = ks * 32 + g * 8;
            union UU { s16x4 h[2]; bf16x8 v; } u0, u1;
            u0.h[0] = tr16(&Vs[cur][0][vr0][c]);
            u0.h[1] = tr16(&Vs[cur][0][vr0 + 4][c]);
            u1.h[0] = tr16(&Vs[cur][1][vr0][c]);
            u1.h[1] = tr16(&Vs[cur][1][vr0 + 4][c]);
            tr_fence();
            const bf16x8 pa = *(const bf16x8*)&Pl[wid][c][ks * 32 + g * 8];
            o0 = __builtin_amdgcn_mfma_f32_16x16x32_bf16(pa, u0.v, o0, 0, 0, 0);
            o1 = __builtin_amdgcn_mfma_f32_16x16x32_bf16(pa, u1.v, o1, 0, 0, 0);
        }
        __builtin_amdgcn_s_setprio(0);
        __syncthreads();
    }
    #undef STAGE

    // ---- finalize: reduce per-lane lsum partials, normalize, store
    float lsum = lpart;
    lsum += __shfl_xor(lsum, 16);
    lsum += __shfl_xor(lsum, 32);
    const float rs = 1.f / lsum;
    float inv[4];
    #pragma unroll
    for (int r = 0; r < 4; ++r) inv[r] = __shfl(rs, g * 4 + r);
    #pragma unroll
    for (int r = 0; r < 4; ++r) {
        ushort* op = out + (size_t)(b * SS + q0 + g * 4 + r) * DMODEL + h * HDIM;
        op[c]      = f2bf(o0[r] * inv[r]);
        op[16 + c] = f2bf(o1[r] * inv[r]);
    }
}

// ---------------------------------------------------------------------------
extern "C" void kernel_launch(void* const* d_in, const int* in_sizes, int n_in,
                              void* d_out, int out_size, void* d_ws, size_t ws_size,
                              hipStream_t stream)
{
    const float* x_in   = (const float*)d_in[0];
    const int*   maskp  = (const int*)d_in[1];
    const float* qkv_w  = (const float*)d_in[2];
    const float* qkv_b  = (const float*)d_in[3];
    const float* fc_w   = (const float*)d_in[4];
    const float* fc_b   = (const float*)d_in[5];
    const float* ln1_g  = (const float*)d_in[6];
    const float* ln1_b  = (const float*)d_in[7];
    const float* ln2_g  = (const float*)d_in[8];
    const float* ln2_b  = (const float*)d_in[9];
    const float* ff1_w  = (const float*)d_in[10];
    const float* ff1_b  = (const float*)d_in[11];
    const float* ff2_w  = (const float*)d_in[12];
    const float* ff2_b  = (const float*)d_in[13];

    float* x = (float*)d_out;                       // [4096,256] fp32 residual

    ushort* wt_qkv = (ushort*)d_ws;                 // [L][768][256]
    ushort* wt_fc  = wt_qkv + (size_t)NL * 768 * 256;
    ushort* wt_ff1 = wt_fc  + (size_t)NL * 256 * 256;
    ushort* wt_ff2 = wt_ff1 + (size_t)NL * 1024 * 256;
    ushort* big    = wt_ff2 + (size_t)NL * 256 * 1024;  // qkv_bf / h_bf (8MB)
    ushort* attn_bf= big + (size_t)MROWS * FFDIM;
    ushort* x_bf   = attn_bf + (size_t)MROWS * DMODEL;

    wconv_all<<<dim3(768, 1, NL), 256, 0, stream>>>(
        qkv_w, fc_w, ff1_w, ff2_w, wt_qkv, wt_fc, wt_ff1, wt_ff2);
    convert_x<<<dim3(MROWS * DMODEL / 1024), 256, 0, stream>>>(x_in, x, x_bf);

    for (int l = 0; l < NL; ++l) {
        // qkv (bf16 out) [4096,768]
        gemm_mfma<64, 128, 2, 2, 0, 1><<<dim3(6, 64), 256, 0, stream>>>(
            x_bf, wt_qkv + (size_t)l * 768 * 256, qkv_b + l * 768,
            nullptr, big, 768, 256);
        // attention -> attn_bf [4096,256] bf16
        attn_mfma6<<<dim3(512), 256, 0, stream>>>(big, maskp, attn_bf);
        // x = LN1(attn @ fc_w + b + x)
        rowgemm_ln<256><<<dim3(256), 256, 0, stream>>>(
            attn_bf, wt_fc + (size_t)l * 256 * 256, fc_b + l * 256,
            ln1_g + l * DMODEL, ln1_b + l * DMODEL, x, x_bf);
        // h = relu(x @ ff1_w + b) (bf16 out) [4096,1024]
        gemm_mfma<128, 128, 2, 2, 1, 1><<<dim3(8, 32), 256, 0, stream>>>(
            x_bf, wt_ff1 + (size_t)l * 1024 * 256, ff1_b + l * FFDIM,
            nullptr, big, 1024, 256);
        // x = LN2(h @ ff2_w + b + x)
        rowgemm_ln<1024><<<dim3(256), 256, 0, stream>>>(
            big, wt_ff2 + (size_t)l * 256 * 1024, ff2_b + l * DMODEL,
            ln2_g + l * DMODEL, ln2_b + l * DMODEL, x, x_bf);
    }
}

// Round 9
// 278.224 us; speedup vs baseline: 1.1507x; 1.0582x over previous
//
#include <hip/hip_runtime.h>
#include <hip/hip_bf16.h>
#include <math.h>

#define NL 4
#define DMODEL 256
#define NH 8
#define FFDIM 1024
#define BB 4
#define SS 1024
#define HDIM 32
#define MROWS (BB * SS)   // 4096
#define LN_EPS 1e-5f

typedef __bf16 bf16x8 __attribute__((ext_vector_type(8)));
typedef float f32x4 __attribute__((ext_vector_type(4)));
typedef short s16x4 __attribute__((ext_vector_type(4)));
typedef unsigned int u32;

__device__ __forceinline__ ushort f2bf(float f) {
    uint u = __builtin_bit_cast(uint, f);
    u += 0x7fff + ((u >> 16) & 1);          // round-to-nearest-even
    return (ushort)(u >> 16);
}
__device__ __forceinline__ uint pack2(float a, float b) {
    return (uint)f2bf(a) | ((uint)f2bf(b) << 16);
}

// async global->LDS, 16B per lane (wave-uniform LDS base + lane*16 layout)
__device__ __forceinline__ void async_ld16(const void* g, void* l) {
    __builtin_amdgcn_global_load_lds(
        (const __attribute__((address_space(1))) u32*)g,
        (__attribute__((address_space(3))) u32*)l, 16, 0, 0);
}

// ds_read_b64_tr_b16: per-lane byte addr A -> 4 bf16 at A, A+32B, A+64B, A+96B
#if __has_builtin(__builtin_amdgcn_ds_read_tr16_b64)
#define TR_BUILTIN 1
#else
#define TR_BUILTIN 0
#endif

__device__ __forceinline__ s16x4 tr16(const ushort* p) {
    __attribute__((address_space(3))) s16x4* ap =
        (__attribute__((address_space(3))) s16x4*)p;
#if TR_BUILTIN
    return __builtin_amdgcn_ds_read_tr16_b64(ap);
#else
    s16x4 r;
    asm volatile("ds_read_b64_tr_b16 %0, %1" : "=v"(r) : "v"(ap) : "memory");
    return r;
#endif
}
__device__ __forceinline__ void tr_fence() {
#if !TR_BUILTIN
    asm volatile("s_waitcnt lgkmcnt(0)" ::: "memory");
    __builtin_amdgcn_sched_barrier(0);
#endif
}

// ---------------------------------------------------------------------------
// All weight transposes in one dispatch. Flat tile id -> {weight, tile}.
// ---------------------------------------------------------------------------
__global__ __launch_bounds__(256)
void wconv_all(const float* __restrict__ qkv_w, const float* __restrict__ fc_w,
               const float* __restrict__ ff1_w, const float* __restrict__ ff2_w,
               ushort* __restrict__ wq, ushort* __restrict__ wfc,
               ushort* __restrict__ wf1, ushort* __restrict__ wf2)
{
    const int l = blockIdx.z;
    int t = blockIdx.x;
    const float* src; ushort* dst; int K, N, nx;
    if (t < 192)      {          src = qkv_w; dst = wq;  K = 256;  N = 768;  nx = 24; }
    else if (t < 256) { t -= 192; src = fc_w;  dst = wfc; K = 256;  N = 256;  nx = 8; }
    else if (t < 512) { t -= 256; src = ff1_w; dst = wf1; K = 256;  N = 1024; nx = 32; }
    else              { t -= 512; src = ff2_w; dst = wf2; K = 1024; N = 256;  nx = 8; }
    src += (size_t)l * K * N;
    dst += (size_t)l * K * N;
    const int n0 = (t % nx) * 32, k0 = (t / nx) * 32;

    __shared__ ushort tt[32][33];
    const int tn = threadIdx.x & 31, tk8 = threadIdx.x >> 5;
    #pragma unroll
    for (int i = 0; i < 4; ++i)
        tt[tn][tk8 + i * 8] = f2bf(src[(size_t)(k0 + tk8 + i * 8) * N + n0 + tn]);
    __syncthreads();
    #pragma unroll
    for (int i = 0; i < 4; ++i)
        dst[(size_t)(n0 + tk8 + i * 8) * K + k0 + tn] = tt[tk8 + i * 8][tn];
}

// ---------------------------------------------------------------------------
// x_in fp32 -> x fp32 (d_out residual stream) + x_bf bf16 mirror
// ---------------------------------------------------------------------------
__global__ __launch_bounds__(256)
void convert_x(const float* __restrict__ xin, float* __restrict__ x,
               ushort* __restrict__ xb)
{
    const size_t i = ((size_t)blockIdx.x * 256 + threadIdx.x) * 4;
    const float4 v = *reinterpret_cast<const float4*>(xin + i);
    *reinterpret_cast<float4*>(x + i) = v;
    uint2 p = make_uint2(pack2(v.x, v.y), pack2(v.z, v.w));
    *reinterpret_cast<uint2*>(xb + i) = p;
}

// ---------------------------------------------------------------------------
// MFMA GEMM: C[M,N] = A[M,K](bf16) @ WT[N,K](bf16)^T + bias, opt ReLU.
// LDS tiles [row][64] with byte-swizzle ^((row&7)<<4): staging pre-swizzles
// the GLOBAL source (global_load_lds dest stays linear), reads XOR the same
// mask -> fragment ds_read_b128 goes 16-way -> 2-way bank conflict (free).
// ---------------------------------------------------------------------------
template<int BM, int BN, int WM, int WN, int ACT, int OBF>
__global__ __launch_bounds__(256)
void gemm_mfma(const ushort* __restrict__ A, const ushort* __restrict__ WT,
               const float* __restrict__ bias, float* __restrict__ Cf,
               ushort* __restrict__ Cb, int N, int K)
{
    constexpr int BK = 64;
    constexpr int WR = BM / WM;
    constexpr int WC = BN / WN;
    constexpr int MR = WR / 16, NR = WC / 16;
    __shared__ __align__(16) ushort As[BM * BK];
    __shared__ __align__(16) ushort Bs[BN * BK];

    const int tid = threadIdx.x;
    const int m0 = blockIdx.y * BM, n0 = blockIdx.x * BN;
    const int wid = tid >> 6, lane = tid & 63;
    const int g = lane >> 4, c = lane & 15;
    const int wr = wid / WN, wc = wid % WN;

    f32x4 acc[MR][NR] = {};

    for (int k0 = 0; k0 < K; k0 += BK) {
        #pragma unroll
        for (int it = 0; it < (BM * BK * 2) / 4096; ++it) {
            const int o = tid * 16 + it * 4096;
            const int r = o >> 7;
            const int cb = (o & 127) ^ ((r & 7) << 4);     // pre-swizzled src
            async_ld16(A + (size_t)(m0 + r) * K + k0 + (cb >> 1), (char*)As + o);
        }
        #pragma unroll
        for (int it = 0; it < (BN * BK * 2) / 4096; ++it) {
            const int o = tid * 16 + it * 4096;
            const int r = o >> 7;
            const int cb = (o & 127) ^ ((r & 7) << 4);
            async_ld16(WT + (size_t)(n0 + r) * K + k0 + (cb >> 1), (char*)Bs + o);
        }
        __syncthreads();

        #pragma unroll
        for (int ks = 0; ks < 2; ++ks) {
            bf16x8 af[MR], bfr[NR];
            #pragma unroll
            for (int mi = 0; mi < MR; ++mi) {
                const int row = wr * WR + mi * 16 + c;
                af[mi] = *(const bf16x8*)((const char*)As
                    + row * 128 + ((ks * 64 + g * 16) ^ ((row & 7) << 4)));
            }
            #pragma unroll
            for (int ni = 0; ni < NR; ++ni) {
                const int row = wc * WC + ni * 16 + c;
                bfr[ni] = *(const bf16x8*)((const char*)Bs
                    + row * 128 + ((ks * 64 + g * 16) ^ ((row & 7) << 4)));
            }
            #pragma unroll
            for (int mi = 0; mi < MR; ++mi)
                #pragma unroll
                for (int ni = 0; ni < NR; ++ni)
                    acc[mi][ni] = __builtin_amdgcn_mfma_f32_16x16x32_bf16(
                        af[mi], bfr[ni], acc[mi][ni], 0, 0, 0);
        }
        __syncthreads();
    }

    float bv[NR];
    #pragma unroll
    for (int ni = 0; ni < NR; ++ni)
        bv[ni] = bias[n0 + wc * WC + ni * 16 + c];

    #pragma unroll
    for (int mi = 0; mi < MR; ++mi) {
        #pragma unroll
        for (int j = 0; j < 4; ++j) {
            const int row = m0 + wr * WR + mi * 16 + g * 4 + j;
            #pragma unroll
            for (int ni = 0; ni < NR; ++ni) {
                float v = acc[mi][ni][j] + bv[ni];
                if (ACT) v = fmaxf(v, 0.f);
                const int col = n0 + wc * WC + ni * 16 + c;
                if (OBF) Cb[(size_t)row * N + col] = f2bf(v);
                else     Cf[(size_t)row * N + col] = v;
            }
        }
    }
}

// ---------------------------------------------------------------------------
// Fused full-row GEMM + residual + LayerNorm (two-pass variance, matches ref).
// BM=16 x N=256, 256 blocks x 256 threads.  Same LDS swizzle as gemm_mfma.
// ---------------------------------------------------------------------------
template<int K>
__global__ __launch_bounds__(256)
void rowgemm_ln(const ushort* __restrict__ A, const ushort* __restrict__ WT,
                const float* __restrict__ bias, const float* __restrict__ lg,
                const float* __restrict__ lb, float* __restrict__ x,
                ushort* __restrict__ xb)
{
    constexpr int BK = 64, N = 256;
    __shared__ __align__(16) ushort As[16 * BK];
    __shared__ __align__(16) ushort Bs[N * BK];
    __shared__ float rsum[4][16], rsq[4][16], mval[16], ival[16];

    const int tid = threadIdx.x;
    const int m0 = blockIdx.x * 16;
    const int wid = tid >> 6, lane = tid & 63;
    const int g = lane >> 4, c = lane & 15;

    f32x4 acc[4] = {};

    for (int k0 = 0; k0 < K; k0 += BK) {
        if (tid < 128) {   // A: 2KB
            const int o = tid * 16;
            const int r = o >> 7;
            const int cb = (o & 127) ^ ((r & 7) << 4);
            async_ld16(A + (size_t)(m0 + r) * K + k0 + (cb >> 1), (char*)As + o);
        }
        #pragma unroll
        for (int it = 0; it < 8; ++it) {   // B: 32KB
            const int o = tid * 16 + it * 4096;
            const int r = o >> 7;
            const int cb = (o & 127) ^ ((r & 7) << 4);
            async_ld16(WT + (size_t)r * K + k0 + (cb >> 1), (char*)Bs + o);
        }
        __syncthreads();

        #pragma unroll
        for (int ks = 0; ks < 2; ++ks) {
            const bf16x8 af = *(const bf16x8*)((const char*)As
                + c * 128 + ((ks * 64 + g * 16) ^ ((c & 7) << 4)));
            #pragma unroll
            for (int ni = 0; ni < 4; ++ni) {
                const int row = wid * 64 + ni * 16 + c;
                const bf16x8 bf = *(const bf16x8*)((const char*)Bs
                    + row * 128 + ((ks * 64 + g * 16) ^ ((row & 7) << 4)));
                acc[ni] = __builtin_amdgcn_mfma_f32_16x16x32_bf16(af, bf, acc[ni], 0, 0, 0);
            }
        }
        __syncthreads();
    }

    float bv[4], glv[4], blv[4];
    #pragma unroll
    for (int ni = 0; ni < 4; ++ni) {
        const int col = wid * 64 + ni * 16 + c;
        bv[ni] = bias[col]; glv[ni] = lg[col]; blv[ni] = lb[col];
    }

    // pass 1: v = acc + bias + residual; row sums -> mean
    #pragma unroll
    for (int j = 0; j < 4; ++j) {
        const int row = g * 4 + j;
        float s = 0.f;
        #pragma unroll
        for (int ni = 0; ni < 4; ++ni) {
            const int col = wid * 64 + ni * 16 + c;
            float vv = acc[ni][j] + bv[ni] + x[(size_t)(m0 + row) * N + col];
            acc[ni][j] = vv;
            s += vv;
        }
        #pragma unroll
        for (int off = 1; off < 16; off <<= 1) s += __shfl_xor(s, off);
        if (c == 0) rsum[wid][row] = s;
    }
    __syncthreads();
    if (tid < 16)
        mval[tid] = (rsum[0][tid] + rsum[1][tid] + rsum[2][tid] + rsum[3][tid])
                    * (1.f / N);
    __syncthreads();

    // pass 2: variance of deviations (matches reference arithmetic)
    #pragma unroll
    for (int j = 0; j < 4; ++j) {
        const int row = g * 4 + j;
        const float mean = mval[row];
        float q = 0.f;
        #pragma unroll
        for (int ni = 0; ni < 4; ++ni) {
            const float d = acc[ni][j] - mean;
            q += d * d;
        }
        #pragma unroll
        for (int off = 1; off < 16; off <<= 1) q += __shfl_xor(q, off);
        if (c == 0) rsq[wid][row] = q;
    }
    __syncthreads();
    if (tid < 16) {
        const float q = rsq[0][tid] + rsq[1][tid] + rsq[2][tid] + rsq[3][tid];
        ival[tid] = rsqrtf(q * (1.f / N) + LN_EPS);
    }
    __syncthreads();

    #pragma unroll
    for (int j = 0; j < 4; ++j) {
        const int row = g * 4 + j;
        const float mean = mval[row], inv = ival[row];
        #pragma unroll
        for (int ni = 0; ni < 4; ++ni) {
            const int col = wid * 64 + ni * 16 + c;
            const float y = (acc[ni][j] - mean) * inv * glv[ni] + blv[ni];
            x[(size_t)(m0 + row) * N + col] = y;
            xb[(size_t)(m0 + row) * N + col] = f2bf(y);
        }
    }
}

// ---------------------------------------------------------------------------
// Flash attention v6b: round-8 structure; Pl stride reverted to 136 ushorts
// (272B rows: lanes c*68 mod 32 -> 8 distinct 4-bank groups = 2-way, free;
// the 144 stride was 4-way).
// ---------------------------------------------------------------------------
__global__ __launch_bounds__(256)
void attn_mfma6(const ushort* __restrict__ qkv, const int* __restrict__ mask,
                ushort* __restrict__ out)
{
    const int tid = threadIdx.x;
    const int lane = tid & 63, wid = tid >> 6;
    const int g = lane >> 4, c = lane & 15;
    const int qblk = blockIdx.x & 15;          // 16 q-blocks of 64
    const int bh = blockIdx.x >> 4;            // 0..31
    const int h = bh & (NH - 1), b = bh >> 3;
    const int q0 = qblk * 64 + wid * 16;

    __shared__ __align__(16) ushort Kb[2][128 * 32];    // [key][32d] 64B rows, swz
    __shared__ __align__(16) ushort Vs[2][2][128][16];  // [dhalf][key][16d]
    __shared__ __align__(16) ushort Pl[4][16][136];     // per-wave [q][key], 272B rows
    __shared__ __align__(16) float  sbias[SS];
    __shared__ int mflag[4];

    const ushort* base  = qkv + (size_t)b * SS * 768;
    const ushort* kbase = base + DMODEL + h * HDIM;
    const ushort* vbase = base + 2 * DMODEL + h * HDIM;

    {   // mask bias + per-wave "any masked" flag
        const int i = tid * 4;
        const int4 mv = *reinterpret_cast<const int4*>(mask + b * SS + i);
        float4 bv;
        bv.x = mv.x ? 0.f : -3.4e38f;
        bv.y = mv.y ? 0.f : -3.4e38f;
        bv.z = mv.z ? 0.f : -3.4e38f;
        bv.w = mv.w ? 0.f : -3.4e38f;
        *reinterpret_cast<float4*>(&sbias[i]) = bv;
        const int miss = __any(!(mv.x && mv.y && mv.z && mv.w));
        if (lane == 0) mflag[wid] = miss;
    }

    const bf16x8 qfrag = *(const bf16x8*)(
        base + (size_t)(q0 + c) * 768 + h * HDIM + g * 8);

    // staging assignments (o16 = tid*16 byte offset; each async covers 4KB)
    const int o16  = tid * 16;
    const int krow = o16 >> 6;                              // key 0..63 (64B rows)
    const int kin  = (o16 & 63) ^ ((krow & 3) << 4);        // swizzled inner bytes
    const int vkey = o16 >> 5;                              // key 0..127 (32B rows)
    const int vd8  = ((o16 >> 4) & 1) << 3;                 // d sub-offset 0/8

    #define STAGE(buf, koff)                                                     \
        do {                                                                     \
            async_ld16(kbase + (size_t)((koff) + krow) * 768 + (kin >> 1),       \
                       (char*)&Kb[buf][0] + o16);                                \
            async_ld16(kbase + (size_t)((koff) + 64 + krow) * 768 + (kin >> 1),  \
                       (char*)&Kb[buf][0] + o16 + 4096);                         \
            async_ld16(vbase + (size_t)((koff) + vkey) * 768 + vd8,              \
                       (char*)&Vs[buf][0][0][0] + o16);                          \
            async_ld16(vbase + (size_t)((koff) + vkey) * 768 + 16 + vd8,         \
                       (char*)&Vs[buf][0][0][0] + o16 + 4096);                   \
        } while (0)

    STAGE(0, 0);
    __syncthreads();
    const int anyMasked = mflag[0] | mflag[1] | mflag[2] | mflag[3];

    float m = -1e30f, lpart = 0.f;
    f32x4 o0 = {0.f, 0.f, 0.f, 0.f}, o1 = {0.f, 0.f, 0.f, 0.f};
    const f32x4 zf = {0.f, 0.f, 0.f, 0.f};

    for (int t = 0; t < 8; ++t) {
        const int cur = t & 1;
        if (t < 7) STAGE(cur ^ 1, (t + 1) * 128);

        // ---- S^T tiles: rows = keys (4/lane), cols = q (=c)
        f32x4 s[8];
        __builtin_amdgcn_s_setprio(1);
        #pragma unroll
        for (int kt = 0; kt < 8; ++kt) {
            const int row = kt * 16 + c;
            const bf16x8 kf = *(const bf16x8*)((const char*)&Kb[cur][0]
                + row * 64 + ((g * 16) ^ ((c & 3) << 4)));
            s[kt] = __builtin_amdgcn_mfma_f32_16x16x32_bf16(kf, qfrag, zf, 0, 0, 0);
        }
        __builtin_amdgcn_s_setprio(0);

        if (anyMasked) {
            #pragma unroll
            for (int kt = 0; kt < 8; ++kt) {
                const f32x4 bv = *reinterpret_cast<const f32x4*>(
                    &sbias[t * 128 + kt * 16 + g * 4]);
                #pragma unroll
                for (int r = 0; r < 4; ++r) s[kt][r] += bv[r];
            }
        }

        // ---- online softmax, defer-rescale (per-lane partial max test)
        float mx = fmaxf(fmaxf(s[0][0], s[0][1]), fmaxf(s[0][2], s[0][3]));
        #pragma unroll
        for (int kt = 1; kt < 8; ++kt)
            mx = fmaxf(mx, fmaxf(fmaxf(s[kt][0], s[kt][1]),
                                 fmaxf(s[kt][2], s[kt][3])));
        if (!__all(mx <= m + 8.f)) {
            float fm = fmaxf(mx, __shfl_xor(mx, 16));
            fm = fmaxf(fm, __shfl_xor(fm, 32));
            const float mn = fmaxf(m, fm);
            const float sc = __expf(m - mn);
            m = mn;
            lpart *= sc;
            float scr[4];
            #pragma unroll
            for (int r = 0; r < 4; ++r) scr[r] = __shfl(sc, g * 4 + r);
            #pragma unroll
            for (int r = 0; r < 4; ++r) { o0[r] *= scr[r]; o1[r] *= scr[r]; }
        }

        float ls = 0.f;
        #pragma unroll
        for (int kt = 0; kt < 8; ++kt) {
            const float p0 = __expf(s[kt][0] - m);
            const float p1 = __expf(s[kt][1] - m);
            const float p2 = __expf(s[kt][2] - m);
            const float p3 = __expf(s[kt][3] - m);
            ls += (p0 + p1) + (p2 + p3);
            uint2 pk2 = make_uint2(pack2(p0, p1), pack2(p2, p3));
            *reinterpret_cast<uint2*>(&Pl[wid][c][kt * 16 + g * 4]) = pk2;
        }
        lpart += ls;

        // ---- PV: O[16q][32d] += P[16q][128k] @ V[128k][32d]
        __builtin_amdgcn_s_setprio(1);
        #pragma unroll
        for (int ks = 0; ks < 4; ++ks) {
            const int vr0 = ks * 32 + g * 8;
            union UU { s16x4 h[2]; bf16x8 v; } u0, u1;
            u0.h[0] = tr16(&Vs[cur][0][vr0][c]);
            u0.h[1] = tr16(&Vs[cur][0][vr0 + 4][c]);
            u1.h[0] = tr16(&Vs[cur][1][vr0][c]);
            u1.h[1] = tr16(&Vs[cur][1][vr0 + 4][c]);
            tr_fence();
            const bf16x8 pa = *(const bf16x8*)&Pl[wid][c][ks * 32 + g * 8];
            o0 = __builtin_amdgcn_mfma_f32_16x16x32_bf16(pa, u0.v, o0, 0, 0, 0);
            o1 = __builtin_amdgcn_mfma_f32_16x16x32_bf16(pa, u1.v, o1, 0, 0, 0);
        }
        __builtin_amdgcn_s_setprio(0);
        __syncthreads();
    }
    #undef STAGE

    // ---- finalize: reduce per-lane lsum partials, normalize, store
    float lsum = lpart;
    lsum += __shfl_xor(lsum, 16);
    lsum += __shfl_xor(lsum, 32);
    const float rs = 1.f / lsum;
    float inv[4];
    #pragma unroll
    for (int r = 0; r < 4; ++r) inv[r] = __shfl(rs, g * 4 + r);
    #pragma unroll
    for (int r = 0; r < 4; ++r) {
        ushort* op = out + (size_t)(b * SS + q0 + g * 4 + r) * DMODEL + h * HDIM;
        op[c]      = f2bf(o0[r] * inv[r]);
        op[16 + c] = f2bf(o1[r] * inv[r]);
    }
}

// ---------------------------------------------------------------------------
extern "C" void kernel_launch(void* const* d_in, const int* in_sizes, int n_in,
                              void* d_out, int out_size, void* d_ws, size_t ws_size,
                              hipStream_t stream)
{
    const float* x_in   = (const float*)d_in[0];
    const int*   maskp  = (const int*)d_in[1];
    const float* qkv_w  = (const float*)d_in[2];
    const float* qkv_b  = (const float*)d_in[3];
    const float* fc_w   = (const float*)d_in[4];
    const float* fc_b   = (const float*)d_in[5];
    const float* ln1_g  = (const float*)d_in[6];
    const float* ln1_b  = (const float*)d_in[7];
    const float* ln2_g  = (const float*)d_in[8];
    const float* ln2_b  = (const float*)d_in[9];
    const float* ff1_w  = (const float*)d_in[10];
    const float* ff1_b  = (const float*)d_in[11];
    const float* ff2_w  = (const float*)d_in[12];
    const float* ff2_b  = (const float*)d_in[13];

    float* x = (float*)d_out;                       // [4096,256] fp32 residual

    ushort* wt_qkv = (ushort*)d_ws;                 // [L][768][256]
    ushort* wt_fc  = wt_qkv + (size_t)NL * 768 * 256;
    ushort* wt_ff1 = wt_fc  + (size_t)NL * 256 * 256;
    ushort* wt_ff2 = wt_ff1 + (size_t)NL * 1024 * 256;
    ushort* big    = wt_ff2 + (size_t)NL * 256 * 1024;  // qkv_bf / h_bf (8MB)
    ushort* attn_bf= big + (size_t)MROWS * FFDIM;
    ushort* x_bf   = attn_bf + (size_t)MROWS * DMODEL;

    wconv_all<<<dim3(768, 1, NL), 256, 0, stream>>>(
        qkv_w, fc_w, ff1_w, ff2_w, wt_qkv, wt_fc, wt_ff1, wt_ff2);
    convert_x<<<dim3(MROWS * DMODEL / 1024), 256, 0, stream>>>(x_in, x, x_bf);

    for (int l = 0; l < NL; ++l) {
        // qkv (bf16 out) [4096,768]
        gemm_mfma<64, 128, 2, 2, 0, 1><<<dim3(6, 64), 256, 0, stream>>>(
            x_bf, wt_qkv + (size_t)l * 768 * 256, qkv_b + l * 768,
            nullptr, big, 768, 256);
        // attention -> attn_bf [4096,256] bf16
        attn_mfma6<<<dim3(512), 256, 0, stream>>>(big, maskp, attn_bf);
        // x = LN1(attn @ fc_w + b + x)
        rowgemm_ln<256><<<dim3(256), 256, 0, stream>>>(
            attn_bf, wt_fc + (size_t)l * 256 * 256, fc_b + l * 256,
            ln1_g + l * DMODEL, ln1_b + l * DMODEL, x, x_bf);
        // h = relu(x @ ff1_w + b) (bf16 out) [4096,1024]
        gemm_mfma<128, 128, 2, 2, 1, 1><<<dim3(8, 32), 256, 0, stream>>>(
            x_bf, wt_ff1 + (size_t)l * 1024 * 256, ff1_b + l * FFDIM,
            nullptr, big, 1024, 256);
        // x = LN2(h @ ff2_w + b + x)
        rowgemm_ln<1024><<<dim3(256), 256, 0, stream>>>(
            big, wt_ff2 + (size_t)l * 256 * 1024, ff2_b + l * DMODEL,
            ln2_g + l * DMODEL, ln2_b + l * DMODEL, x, x_bf);
    }
}

// Round 10
// 274.472 us; speedup vs baseline: 1.1665x; 1.0137x over previous
//
#include <hip/hip_runtime.h>
#include <hip/hip_bf16.h>
#include <math.h>

#define NL 4
#define DMODEL 256
#define NH 8
#define FFDIM 1024
#define BB 4
#define SS 1024
#define HDIM 32
#define MROWS (BB * SS)   // 4096
#define LN_EPS 1e-5f

typedef __bf16 bf16x8 __attribute__((ext_vector_type(8)));
typedef float f32x4 __attribute__((ext_vector_type(4)));
typedef short s16x4 __attribute__((ext_vector_type(4)));
typedef unsigned int u32;

__device__ __forceinline__ ushort f2bf(float f) {
    uint u = __builtin_bit_cast(uint, f);
    u += 0x7fff + ((u >> 16) & 1);          // round-to-nearest-even
    return (ushort)(u >> 16);
}
__device__ __forceinline__ uint pack2(float a, float b) {
    return (uint)f2bf(a) | ((uint)f2bf(b) << 16);
}

// async global->LDS, 16B per lane (wave-uniform LDS base + lane*16 layout)
__device__ __forceinline__ void async_ld16(const void* g, void* l) {
    __builtin_amdgcn_global_load_lds(
        (const __attribute__((address_space(1))) u32*)g,
        (__attribute__((address_space(3))) u32*)l, 16, 0, 0);
}

// ds_read_b64_tr_b16: per-lane byte addr A -> 4 bf16 at A, A+32B, A+64B, A+96B
#if __has_builtin(__builtin_amdgcn_ds_read_tr16_b64)
#define TR_BUILTIN 1
#else
#define TR_BUILTIN 0
#endif

__device__ __forceinline__ s16x4 tr16(const ushort* p) {
    __attribute__((address_space(3))) s16x4* ap =
        (__attribute__((address_space(3))) s16x4*)p;
#if TR_BUILTIN
    return __builtin_amdgcn_ds_read_tr16_b64(ap);
#else
    s16x4 r;
    asm volatile("ds_read_b64_tr_b16 %0, %1" : "=v"(r) : "v"(ap) : "memory");
    return r;
#endif
}
__device__ __forceinline__ void tr_fence() {
#if !TR_BUILTIN
    asm volatile("s_waitcnt lgkmcnt(0)" ::: "memory");
    __builtin_amdgcn_sched_barrier(0);
#endif
}

// ---------------------------------------------------------------------------
// All weight transposes in one dispatch. Flat tile id -> {weight, tile}.
// ---------------------------------------------------------------------------
__global__ __launch_bounds__(256)
void wconv_all(const float* __restrict__ qkv_w, const float* __restrict__ fc_w,
               const float* __restrict__ ff1_w, const float* __restrict__ ff2_w,
               ushort* __restrict__ wq, ushort* __restrict__ wfc,
               ushort* __restrict__ wf1, ushort* __restrict__ wf2)
{
    const int l = blockIdx.z;
    int t = blockIdx.x;
    const float* src; ushort* dst; int K, N, nx;
    if (t < 192)      {          src = qkv_w; dst = wq;  K = 256;  N = 768;  nx = 24; }
    else if (t < 256) { t -= 192; src = fc_w;  dst = wfc; K = 256;  N = 256;  nx = 8; }
    else if (t < 512) { t -= 256; src = ff1_w; dst = wf1; K = 256;  N = 1024; nx = 32; }
    else              { t -= 512; src = ff2_w; dst = wf2; K = 1024; N = 256;  nx = 8; }
    src += (size_t)l * K * N;
    dst += (size_t)l * K * N;
    const int n0 = (t % nx) * 32, k0 = (t / nx) * 32;

    __shared__ ushort tt[32][33];
    const int tn = threadIdx.x & 31, tk8 = threadIdx.x >> 5;
    #pragma unroll
    for (int i = 0; i < 4; ++i)
        tt[tn][tk8 + i * 8] = f2bf(src[(size_t)(k0 + tk8 + i * 8) * N + n0 + tn]);
    __syncthreads();
    #pragma unroll
    for (int i = 0; i < 4; ++i)
        dst[(size_t)(n0 + tk8 + i * 8) * K + k0 + tn] = tt[tk8 + i * 8][tn];
}

// ---------------------------------------------------------------------------
// x_in fp32 -> x fp32 (d_out residual stream) + x_bf bf16 mirror
// ---------------------------------------------------------------------------
__global__ __launch_bounds__(256)
void convert_x(const float* __restrict__ xin, float* __restrict__ x,
               ushort* __restrict__ xb)
{
    const size_t i = ((size_t)blockIdx.x * 256 + threadIdx.x) * 4;
    const float4 v = *reinterpret_cast<const float4*>(xin + i);
    *reinterpret_cast<float4*>(x + i) = v;
    uint2 p = make_uint2(pack2(v.x, v.y), pack2(v.z, v.w));
    *reinterpret_cast<uint2*>(xb + i) = p;
}

// ---------------------------------------------------------------------------
// MFMA GEMM, 2-phase double-buffered: STAGE(next K-tile) issued BEFORE the
// compute of the current tile; ONE barrier per K-step (its implicit vmcnt(0)
// drain is covered by the current tile's MFMAs).  LDS swizzle ^((row&7)<<4)
// via pre-swizzled global source (round-9 verified).
// ---------------------------------------------------------------------------
template<int BM, int BN, int WM, int WN, int ACT, int OBF>
__global__ __launch_bounds__(256)
void gemm_mfma(const ushort* __restrict__ A, const ushort* __restrict__ WT,
               const float* __restrict__ bias, float* __restrict__ Cf,
               ushort* __restrict__ Cb, int N, int K)
{
    constexpr int BK = 64;
    constexpr int WR = BM / WM;
    constexpr int WC = BN / WN;
    constexpr int MR = WR / 16, NR = WC / 16;
    __shared__ __align__(16) ushort As[2][BM * BK];
    __shared__ __align__(16) ushort Bs[2][BN * BK];

    const int tid = threadIdx.x;
    const int m0 = blockIdx.y * BM, n0 = blockIdx.x * BN;
    const int wid = tid >> 6, lane = tid & 63;
    const int g = lane >> 4, c = lane & 15;
    const int wr = wid / WN, wc = wid % WN;

    auto stage = [&](int buf, int k0) {
        #pragma unroll
        for (int it = 0; it < (BM * BK * 2) / 4096; ++it) {
            const int o = tid * 16 + it * 4096;
            const int r = o >> 7;
            const int cb = (o & 127) ^ ((r & 7) << 4);     // pre-swizzled src
            async_ld16(A + (size_t)(m0 + r) * K + k0 + (cb >> 1),
                       (char*)&As[buf][0] + o);
        }
        #pragma unroll
        for (int it = 0; it < (BN * BK * 2) / 4096; ++it) {
            const int o = tid * 16 + it * 4096;
            const int r = o >> 7;
            const int cb = (o & 127) ^ ((r & 7) << 4);
            async_ld16(WT + (size_t)(n0 + r) * K + k0 + (cb >> 1),
                       (char*)&Bs[buf][0] + o);
        }
    };

    f32x4 acc[MR][NR] = {};

    stage(0, 0);
    __syncthreads();

    int cur = 0;
    for (int k0 = 0; k0 < K; k0 += BK, cur ^= 1) {
        if (k0 + BK < K) stage(cur ^ 1, k0 + BK);

        #pragma unroll
        for (int ks = 0; ks < 2; ++ks) {
            bf16x8 af[MR], bfr[NR];
            #pragma unroll
            for (int mi = 0; mi < MR; ++mi) {
                const int row = wr * WR + mi * 16 + c;
                af[mi] = *(const bf16x8*)((const char*)&As[cur][0]
                    + row * 128 + ((ks * 64 + g * 16) ^ ((row & 7) << 4)));
            }
            #pragma unroll
            for (int ni = 0; ni < NR; ++ni) {
                const int row = wc * WC + ni * 16 + c;
                bfr[ni] = *(const bf16x8*)((const char*)&Bs[cur][0]
                    + row * 128 + ((ks * 64 + g * 16) ^ ((row & 7) << 4)));
            }
            #pragma unroll
            for (int mi = 0; mi < MR; ++mi)
                #pragma unroll
                for (int ni = 0; ni < NR; ++ni)
                    acc[mi][ni] = __builtin_amdgcn_mfma_f32_16x16x32_bf16(
                        af[mi], bfr[ni], acc[mi][ni], 0, 0, 0);
        }
        __syncthreads();
    }

    float bv[NR];
    #pragma unroll
    for (int ni = 0; ni < NR; ++ni)
        bv[ni] = bias[n0 + wc * WC + ni * 16 + c];

    #pragma unroll
    for (int mi = 0; mi < MR; ++mi) {
        #pragma unroll
        for (int j = 0; j < 4; ++j) {
            const int row = m0 + wr * WR + mi * 16 + g * 4 + j;
            #pragma unroll
            for (int ni = 0; ni < NR; ++ni) {
                float v = acc[mi][ni][j] + bv[ni];
                if (ACT) v = fmaxf(v, 0.f);
                const int col = n0 + wc * WC + ni * 16 + c;
                if (OBF) Cb[(size_t)row * N + col] = f2bf(v);
                else     Cf[(size_t)row * N + col] = v;
            }
        }
    }
}

// ---------------------------------------------------------------------------
// Fused full-row GEMM + residual + LayerNorm (two-pass variance), 2-phase
// double-buffered like gemm_mfma.  BM=16 x N=256, 256 blocks x 256 threads.
// ---------------------------------------------------------------------------
template<int K>
__global__ __launch_bounds__(256)
void rowgemm_ln(const ushort* __restrict__ A, const ushort* __restrict__ WT,
                const float* __restrict__ bias, const float* __restrict__ lg,
                const float* __restrict__ lb, float* __restrict__ x,
                ushort* __restrict__ xb)
{
    constexpr int BK = 64, N = 256;
    __shared__ __align__(16) ushort As[2][16 * BK];
    __shared__ __align__(16) ushort Bs[2][N * BK];
    __shared__ float rsum[4][16], rsq[4][16], mval[16], ival[16];

    const int tid = threadIdx.x;
    const int m0 = blockIdx.x * 16;
    const int wid = tid >> 6, lane = tid & 63;
    const int g = lane >> 4, c = lane & 15;

    auto stage = [&](int buf, int k0) {
        if (tid < 128) {   // A: 2KB
            const int o = tid * 16;
            const int r = o >> 7;
            const int cb = (o & 127) ^ ((r & 7) << 4);
            async_ld16(A + (size_t)(m0 + r) * K + k0 + (cb >> 1),
                       (char*)&As[buf][0] + o);
        }
        #pragma unroll
        for (int it = 0; it < 8; ++it) {   // B: 32KB
            const int o = tid * 16 + it * 4096;
            const int r = o >> 7;
            const int cb = (o & 127) ^ ((r & 7) << 4);
            async_ld16(WT + (size_t)r * K + k0 + (cb >> 1),
                       (char*)&Bs[buf][0] + o);
        }
    };

    f32x4 acc[4] = {};

    stage(0, 0);
    __syncthreads();

    int cur = 0;
    for (int k0 = 0; k0 < K; k0 += BK, cur ^= 1) {
        if (k0 + BK < K) stage(cur ^ 1, k0 + BK);

        #pragma unroll
        for (int ks = 0; ks < 2; ++ks) {
            const bf16x8 af = *(const bf16x8*)((const char*)&As[cur][0]
                + c * 128 + ((ks * 64 + g * 16) ^ ((c & 7) << 4)));
            #pragma unroll
            for (int ni = 0; ni < 4; ++ni) {
                const int row = wid * 64 + ni * 16 + c;
                const bf16x8 bf = *(const bf16x8*)((const char*)&Bs[cur][0]
                    + row * 128 + ((ks * 64 + g * 16) ^ ((row & 7) << 4)));
                acc[ni] = __builtin_amdgcn_mfma_f32_16x16x32_bf16(af, bf, acc[ni], 0, 0, 0);
            }
        }
        __syncthreads();
    }

    float bv[4], glv[4], blv[4];
    #pragma unroll
    for (int ni = 0; ni < 4; ++ni) {
        const int col = wid * 64 + ni * 16 + c;
        bv[ni] = bias[col]; glv[ni] = lg[col]; blv[ni] = lb[col];
    }

    // pass 1: v = acc + bias + residual; row sums -> mean
    #pragma unroll
    for (int j = 0; j < 4; ++j) {
        const int row = g * 4 + j;
        float s = 0.f;
        #pragma unroll
        for (int ni = 0; ni < 4; ++ni) {
            const int col = wid * 64 + ni * 16 + c;
            float vv = acc[ni][j] + bv[ni] + x[(size_t)(m0 + row) * N + col];
            acc[ni][j] = vv;
            s += vv;
        }
        #pragma unroll
        for (int off = 1; off < 16; off <<= 1) s += __shfl_xor(s, off);
        if (c == 0) rsum[wid][row] = s;
    }
    __syncthreads();
    if (tid < 16)
        mval[tid] = (rsum[0][tid] + rsum[1][tid] + rsum[2][tid] + rsum[3][tid])
                    * (1.f / N);
    __syncthreads();

    // pass 2: variance of deviations (matches reference arithmetic)
    #pragma unroll
    for (int j = 0; j < 4; ++j) {
        const int row = g * 4 + j;
        const float mean = mval[row];
        float q = 0.f;
        #pragma unroll
        for (int ni = 0; ni < 4; ++ni) {
            const float d = acc[ni][j] - mean;
            q += d * d;
        }
        #pragma unroll
        for (int off = 1; off < 16; off <<= 1) q += __shfl_xor(q, off);
        if (c == 0) rsq[wid][row] = q;
    }
    __syncthreads();
    if (tid < 16) {
        const float q = rsq[0][tid] + rsq[1][tid] + rsq[2][tid] + rsq[3][tid];
        ival[tid] = rsqrtf(q * (1.f / N) + LN_EPS);
    }
    __syncthreads();

    #pragma unroll
    for (int j = 0; j < 4; ++j) {
        const int row = g * 4 + j;
        const float mean = mval[row], inv = ival[row];
        #pragma unroll
        for (int ni = 0; ni < 4; ++ni) {
            const int col = wid * 64 + ni * 16 + c;
            const float y = (acc[ni][j] - mean) * inv * glv[ni] + blv[ni];
            x[(size_t)(m0 + row) * N + col] = y;
            xb[(size_t)(m0 + row) * N + col] = f2bf(y);
        }
    }
}

// ---------------------------------------------------------------------------
// Flash attention v6b (round-9 verified, unchanged).
// ---------------------------------------------------------------------------
__global__ __launch_bounds__(256)
void attn_mfma6(const ushort* __restrict__ qkv, const int* __restrict__ mask,
                ushort* __restrict__ out)
{
    const int tid = threadIdx.x;
    const int lane = tid & 63, wid = tid >> 6;
    const int g = lane >> 4, c = lane & 15;
    const int qblk = blockIdx.x & 15;          // 16 q-blocks of 64
    const int bh = blockIdx.x >> 4;            // 0..31
    const int h = bh & (NH - 1), b = bh >> 3;
    const int q0 = qblk * 64 + wid * 16;

    __shared__ __align__(16) ushort Kb[2][128 * 32];    // [key][32d] 64B rows, swz
    __shared__ __align__(16) ushort Vs[2][2][128][16];  // [dhalf][key][16d]
    __shared__ __align__(16) ushort Pl[4][16][136];     // per-wave [q][key], 272B rows
    __shared__ __align__(16) float  sbias[SS];
    __shared__ int mflag[4];

    const ushort* base  = qkv + (size_t)b * SS * 768;
    const ushort* kbase = base + DMODEL + h * HDIM;
    const ushort* vbase = base + 2 * DMODEL + h * HDIM;

    {   // mask bias + per-wave "any masked" flag
        const int i = tid * 4;
        const int4 mv = *reinterpret_cast<const int4*>(mask + b * SS + i);
        float4 bv;
        bv.x = mv.x ? 0.f : -3.4e38f;
        bv.y = mv.y ? 0.f : -3.4e38f;
        bv.z = mv.z ? 0.f : -3.4e38f;
        bv.w = mv.w ? 0.f : -3.4e38f;
        *reinterpret_cast<float4*>(&sbias[i]) = bv;
        const int miss = __any(!(mv.x && mv.y && mv.z && mv.w));
        if (lane == 0) mflag[wid] = miss;
    }

    const bf16x8 qfrag = *(const bf16x8*)(
        base + (size_t)(q0 + c) * 768 + h * HDIM + g * 8);

    // staging assignments (o16 = tid*16 byte offset; each async covers 4KB)
    const int o16  = tid * 16;
    const int krow = o16 >> 6;                              // key 0..63 (64B rows)
    const int kin  = (o16 & 63) ^ ((krow & 3) << 4);        // swizzled inner bytes
    const int vkey = o16 >> 5;                              // key 0..127 (32B rows)
    const int vd8  = ((o16 >> 4) & 1) << 3;                 // d sub-offset 0/8

    #define STAGE(buf, koff)                                                     \
        do {                                                                     \
            async_ld16(kbase + (size_t)((koff) + krow) * 768 + (kin >> 1),       \
                       (char*)&Kb[buf][0] + o16);                                \
            async_ld16(kbase + (size_t)((koff) + 64 + krow) * 768 + (kin >> 1),  \
                       (char*)&Kb[buf][0] + o16 + 4096);                         \
            async_ld16(vbase + (size_t)((koff) + vkey) * 768 + vd8,              \
                       (char*)&Vs[buf][0][0][0] + o16);                          \
            async_ld16(vbase + (size_t)((koff) + vkey) * 768 + 16 + vd8,         \
                       (char*)&Vs[buf][0][0][0] + o16 + 4096);                   \
        } while (0)

    STAGE(0, 0);
    __syncthreads();
    const int anyMasked = mflag[0] | mflag[1] | mflag[2] | mflag[3];

    float m = -1e30f, lpart = 0.f;
    f32x4 o0 = {0.f, 0.f, 0.f, 0.f}, o1 = {0.f, 0.f, 0.f, 0.f};
    const f32x4 zf = {0.f, 0.f, 0.f, 0.f};

    for (int t = 0; t < 8; ++t) {
        const int cur = t & 1;
        if (t < 7) STAGE(cur ^ 1, (t + 1) * 128);

        // ---- S^T tiles: rows = keys (4/lane), cols = q (=c)
        f32x4 s[8];
        __builtin_amdgcn_s_setprio(1);
        #pragma unroll
        for (int kt = 0; kt < 8; ++kt) {
            const int row = kt * 16 + c;
            const bf16x8 kf = *(const bf16x8*)((const char*)&Kb[cur][0]
                + row * 64 + ((g * 16) ^ ((c & 3) << 4)));
            s[kt] = __builtin_amdgcn_mfma_f32_16x16x32_bf16(kf, qfrag, zf, 0, 0, 0);
        }
        __builtin_amdgcn_s_setprio(0);

        if (anyMasked) {
            #pragma unroll
            for (int kt = 0; kt < 8; ++kt) {
                const f32x4 bv = *reinterpret_cast<const f32x4*>(
                    &sbias[t * 128 + kt * 16 + g * 4]);
                #pragma unroll
                for (int r = 0; r < 4; ++r) s[kt][r] += bv[r];
            }
        }

        // ---- online softmax, defer-rescale (per-lane partial max test)
        float mx = fmaxf(fmaxf(s[0][0], s[0][1]), fmaxf(s[0][2], s[0][3]));
        #pragma unroll
        for (int kt = 1; kt < 8; ++kt)
            mx = fmaxf(mx, fmaxf(fmaxf(s[kt][0], s[kt][1]),
                                 fmaxf(s[kt][2], s[kt][3])));
        if (!__all(mx <= m + 8.f)) {
            float fm = fmaxf(mx, __shfl_xor(mx, 16));
            fm = fmaxf(fm, __shfl_xor(fm, 32));
            const float mn = fmaxf(m, fm);
            const float sc = __expf(m - mn);
            m = mn;
            lpart *= sc;
            float scr[4];
            #pragma unroll
            for (int r = 0; r < 4; ++r) scr[r] = __shfl(sc, g * 4 + r);
            #pragma unroll
            for (int r = 0; r < 4; ++r) { o0[r] *= scr[r]; o1[r] *= scr[r]; }
        }

        float ls = 0.f;
        #pragma unroll
        for (int kt = 0; kt < 8; ++kt) {
            const float p0 = __expf(s[kt][0] - m);
            const float p1 = __expf(s[kt][1] - m);
            const float p2 = __expf(s[kt][2] - m);
            const float p3 = __expf(s[kt][3] - m);
            ls += (p0 + p1) + (p2 + p3);
            uint2 pk2 = make_uint2(pack2(p0, p1), pack2(p2, p3));
            *reinterpret_cast<uint2*>(&Pl[wid][c][kt * 16 + g * 4]) = pk2;
        }
        lpart += ls;

        // ---- PV: O[16q][32d] += P[16q][128k] @ V[128k][32d]
        __builtin_amdgcn_s_setprio(1);
        #pragma unroll
        for (int ks = 0; ks < 4; ++ks) {
            const int vr0 = ks * 32 + g * 8;
            union UU { s16x4 h[2]; bf16x8 v; } u0, u1;
            u0.h[0] = tr16(&Vs[cur][0][vr0][c]);
            u0.h[1] = tr16(&Vs[cur][0][vr0 + 4][c]);
            u1.h[0] = tr16(&Vs[cur][1][vr0][c]);
            u1.h[1] = tr16(&Vs[cur][1][vr0 + 4][c]);
            tr_fence();
            const bf16x8 pa = *(const bf16x8*)&Pl[wid][c][ks * 32 + g * 8];
            o0 = __builtin_amdgcn_mfma_f32_16x16x32_bf16(pa, u0.v, o0, 0, 0, 0);
            o1 = __builtin_amdgcn_mfma_f32_16x16x32_bf16(pa, u1.v, o1, 0, 0, 0);
        }
        __builtin_amdgcn_s_setprio(0);
        __syncthreads();
    }
    #undef STAGE

    // ---- finalize: reduce per-lane lsum partials, normalize, store
    float lsum = lpart;
    lsum += __shfl_xor(lsum, 16);
    lsum += __shfl_xor(lsum, 32);
    const float rs = 1.f / lsum;
    float inv[4];
    #pragma unroll
    for (int r = 0; r < 4; ++r) inv[r] = __shfl(rs, g * 4 + r);
    #pragma unroll
    for (int r = 0; r < 4; ++r) {
        ushort* op = out + (size_t)(b * SS + q0 + g * 4 + r) * DMODEL + h * HDIM;
        op[c]      = f2bf(o0[r] * inv[r]);
        op[16 + c] = f2bf(o1[r] * inv[r]);
    }
}

// ---------------------------------------------------------------------------
extern "C" void kernel_launch(void* const* d_in, const int* in_sizes, int n_in,
                              void* d_out, int out_size, void* d_ws, size_t ws_size,
                              hipStream_t stream)
{
    const float* x_in   = (const float*)d_in[0];
    const int*   maskp  = (const int*)d_in[1];
    const float* qkv_w  = (const float*)d_in[2];
    const float* qkv_b  = (const float*)d_in[3];
    const float* fc_w   = (const float*)d_in[4];
    const float* fc_b   = (const float*)d_in[5];
    const float* ln1_g  = (const float*)d_in[6];
    const float* ln1_b  = (const float*)d_in[7];
    const float* ln2_g  = (const float*)d_in[8];
    const float* ln2_b  = (const float*)d_in[9];
    const float* ff1_w  = (const float*)d_in[10];
    const float* ff1_b  = (const float*)d_in[11];
    const float* ff2_w  = (const float*)d_in[12];
    const float* ff2_b  = (const float*)d_in[13];

    float* x = (float*)d_out;                       // [4096,256] fp32 residual

    ushort* wt_qkv = (ushort*)d_ws;                 // [L][768][256]
    ushort* wt_fc  = wt_qkv + (size_t)NL * 768 * 256;
    ushort* wt_ff1 = wt_fc  + (size_t)NL * 256 * 256;
    ushort* wt_ff2 = wt_ff1 + (size_t)NL * 1024 * 256;
    ushort* big    = wt_ff2 + (size_t)NL * 256 * 1024;  // qkv_bf / h_bf (8MB)
    ushort* attn_bf= big + (size_t)MROWS * FFDIM;
    ushort* x_bf   = attn_bf + (size_t)MROWS * DMODEL;

    wconv_all<<<dim3(768, 1, NL), 256, 0, stream>>>(
        qkv_w, fc_w, ff1_w, ff2_w, wt_qkv, wt_fc, wt_ff1, wt_ff2);
    convert_x<<<dim3(MROWS * DMODEL / 1024), 256, 0, stream>>>(x_in, x, x_bf);

    for (int l = 0; l < NL; ++l) {
        // qkv (bf16 out) [4096,768]
        gemm_mfma<64, 128, 2, 2, 0, 1><<<dim3(6, 64), 256, 0, stream>>>(
            x_bf, wt_qkv + (size_t)l * 768 * 256, qkv_b + l * 768,
            nullptr, big, 768, 256);
        // attention -> attn_bf [4096,256] bf16
        attn_mfma6<<<dim3(512), 256, 0, stream>>>(big, maskp, attn_bf);
        // x = LN1(attn @ fc_w + b + x)
        rowgemm_ln<256><<<dim3(256), 256, 0, stream>>>(
            attn_bf, wt_fc + (size_t)l * 256 * 256, fc_b + l * 256,
            ln1_g + l * DMODEL, ln1_b + l * DMODEL, x, x_bf);
        // h = relu(x @ ff1_w + b) (bf16 out) [4096,1024]
        gemm_mfma<128, 128, 2, 2, 1, 1><<<dim3(8, 32), 256, 0, stream>>>(
            x_bf, wt_ff1 + (size_t)l * 1024 * 256, ff1_b + l * FFDIM,
            nullptr, big, 1024, 256);
        // x = LN2(h @ ff2_w + b + x)
        rowgemm_ln<1024><<<dim3(256), 256, 0, stream>>>(
            big, wt_ff2 + (size_t)l * 256 * 1024, ff2_b + l * DMODEL,
            ln2_g + l * DMODEL, ln2_b + l * DMODEL, x, x_bf);
    }
}

// Round 11
// 266.027 us; speedup vs baseline: 1.2035x; 1.0317x over previous
//
#include <hip/hip_runtime.h>
#include <hip/hip_bf16.h>
#include <math.h>

#define NL 4
#define DMODEL 256
#define NH 8
#define FFDIM 1024
#define BB 4
#define SS 1024
#define HDIM 32
#define MROWS (BB * SS)   // 4096
#define LN_EPS 1e-5f

typedef __bf16 bf16x8 __attribute__((ext_vector_type(8)));
typedef float f32x4 __attribute__((ext_vector_type(4)));
typedef short s16x4 __attribute__((ext_vector_type(4)));
typedef unsigned int u32;

__device__ __forceinline__ ushort f2bf(float f) {
    uint u = __builtin_bit_cast(uint, f);
    u += 0x7fff + ((u >> 16) & 1);          // round-to-nearest-even
    return (ushort)(u >> 16);
}
__device__ __forceinline__ uint pack2(float a, float b) {
    return (uint)f2bf(a) | ((uint)f2bf(b) << 16);
}

// XCD-chunked block swizzle (T1).  nwg % 8 == 0 -> bijective.
// HW round-robins launch-index across 8 XCDs; this gives XCD k a CONTIGUOUS
// chunk of the work space so blocks sharing operand panels share one L2.
__device__ __forceinline__ int xcd_swz(int bid, int nwg) {
    return (bid & 7) * (nwg >> 3) + (bid >> 3);
}

// async global->LDS, 16B per lane (wave-uniform LDS base + lane*16 layout)
__device__ __forceinline__ void async_ld16(const void* g, void* l) {
    __builtin_amdgcn_global_load_lds(
        (const __attribute__((address_space(1))) u32*)g,
        (__attribute__((address_space(3))) u32*)l, 16, 0, 0);
}

// ds_read_b64_tr_b16: per-lane byte addr A -> 4 bf16 at A, A+32B, A+64B, A+96B
#if __has_builtin(__builtin_amdgcn_ds_read_tr16_b64)
#define TR_BUILTIN 1
#else
#define TR_BUILTIN 0
#endif

__device__ __forceinline__ s16x4 tr16(const ushort* p) {
    __attribute__((address_space(3))) s16x4* ap =
        (__attribute__((address_space(3))) s16x4*)p;
#if TR_BUILTIN
    return __builtin_amdgcn_ds_read_tr16_b64(ap);
#else
    s16x4 r;
    asm volatile("ds_read_b64_tr_b16 %0, %1" : "=v"(r) : "v"(ap) : "memory");
    return r;
#endif
}
__device__ __forceinline__ void tr_fence() {
#if !TR_BUILTIN
    asm volatile("s_waitcnt lgkmcnt(0)" ::: "memory");
    __builtin_amdgcn_sched_barrier(0);
#endif
}

// ---------------------------------------------------------------------------
// All weight transposes in one dispatch. Flat tile id -> {weight, tile}.
// ---------------------------------------------------------------------------
__global__ __launch_bounds__(256)
void wconv_all(const float* __restrict__ qkv_w, const float* __restrict__ fc_w,
               const float* __restrict__ ff1_w, const float* __restrict__ ff2_w,
               ushort* __restrict__ wq, ushort* __restrict__ wfc,
               ushort* __restrict__ wf1, ushort* __restrict__ wf2)
{
    const int l = blockIdx.z;
    int t = blockIdx.x;
    const float* src; ushort* dst; int K, N, nx;
    if (t < 192)      {          src = qkv_w; dst = wq;  K = 256;  N = 768;  nx = 24; }
    else if (t < 256) { t -= 192; src = fc_w;  dst = wfc; K = 256;  N = 256;  nx = 8; }
    else if (t < 512) { t -= 256; src = ff1_w; dst = wf1; K = 256;  N = 1024; nx = 32; }
    else              { t -= 512; src = ff2_w; dst = wf2; K = 1024; N = 256;  nx = 8; }
    src += (size_t)l * K * N;
    dst += (size_t)l * K * N;
    const int n0 = (t % nx) * 32, k0 = (t / nx) * 32;

    __shared__ ushort tt[32][33];
    const int tn = threadIdx.x & 31, tk8 = threadIdx.x >> 5;
    #pragma unroll
    for (int i = 0; i < 4; ++i)
        tt[tn][tk8 + i * 8] = f2bf(src[(size_t)(k0 + tk8 + i * 8) * N + n0 + tn]);
    __syncthreads();
    #pragma unroll
    for (int i = 0; i < 4; ++i)
        dst[(size_t)(n0 + tk8 + i * 8) * K + k0 + tn] = tt[tk8 + i * 8][tn];
}

// ---------------------------------------------------------------------------
// x_in fp32 -> x fp32 (d_out residual stream) + x_bf bf16 mirror
// ---------------------------------------------------------------------------
__global__ __launch_bounds__(256)
void convert_x(const float* __restrict__ xin, float* __restrict__ x,
               ushort* __restrict__ xb)
{
    const size_t i = ((size_t)blockIdx.x * 256 + threadIdx.x) * 4;
    const float4 v = *reinterpret_cast<const float4*>(xin + i);
    *reinterpret_cast<float4*>(x + i) = v;
    uint2 p = make_uint2(pack2(v.x, v.y), pack2(v.z, v.w));
    *reinterpret_cast<uint2*>(xb + i) = p;
}

// ---------------------------------------------------------------------------
// MFMA GEMM, 2-phase double-buffered, LDS swizzle (round-10 verified) +
// XCD-chunked block swizzle over the flattened grid.
// ---------------------------------------------------------------------------
template<int BM, int BN, int WM, int WN, int ACT, int OBF>
__global__ __launch_bounds__(256)
void gemm_mfma(const ushort* __restrict__ A, const ushort* __restrict__ WT,
               const float* __restrict__ bias, float* __restrict__ Cf,
               ushort* __restrict__ Cb, int N, int K)
{
    constexpr int BK = 64;
    constexpr int WR = BM / WM;
    constexpr int WC = BN / WN;
    constexpr int MR = WR / 16, NR = WC / 16;
    __shared__ __align__(16) ushort As[2][BM * BK];
    __shared__ __align__(16) ushort Bs[2][BN * BK];

    const int tid = threadIdx.x;
    // XCD swizzle over flattened launch index (x fastest)
    const int lin = blockIdx.y * gridDim.x + blockIdx.x;
    const int work = xcd_swz(lin, gridDim.x * gridDim.y);
    const int m0 = (work / gridDim.x) * BM, n0 = (work % gridDim.x) * BN;
    const int wid = tid >> 6, lane = tid & 63;
    const int g = lane >> 4, c = lane & 15;
    const int wr = wid / WN, wc = wid % WN;

    auto stage = [&](int buf, int k0) {
        #pragma unroll
        for (int it = 0; it < (BM * BK * 2) / 4096; ++it) {
            const int o = tid * 16 + it * 4096;
            const int r = o >> 7;
            const int cb = (o & 127) ^ ((r & 7) << 4);     // pre-swizzled src
            async_ld16(A + (size_t)(m0 + r) * K + k0 + (cb >> 1),
                       (char*)&As[buf][0] + o);
        }
        #pragma unroll
        for (int it = 0; it < (BN * BK * 2) / 4096; ++it) {
            const int o = tid * 16 + it * 4096;
            const int r = o >> 7;
            const int cb = (o & 127) ^ ((r & 7) << 4);
            async_ld16(WT + (size_t)(n0 + r) * K + k0 + (cb >> 1),
                       (char*)&Bs[buf][0] + o);
        }
    };

    f32x4 acc[MR][NR] = {};

    stage(0, 0);
    __syncthreads();

    int cur = 0;
    for (int k0 = 0; k0 < K; k0 += BK, cur ^= 1) {
        if (k0 + BK < K) stage(cur ^ 1, k0 + BK);

        #pragma unroll
        for (int ks = 0; ks < 2; ++ks) {
            bf16x8 af[MR], bfr[NR];
            #pragma unroll
            for (int mi = 0; mi < MR; ++mi) {
                const int row = wr * WR + mi * 16 + c;
                af[mi] = *(const bf16x8*)((const char*)&As[cur][0]
                    + row * 128 + ((ks * 64 + g * 16) ^ ((row & 7) << 4)));
            }
            #pragma unroll
            for (int ni = 0; ni < NR; ++ni) {
                const int row = wc * WC + ni * 16 + c;
                bfr[ni] = *(const bf16x8*)((const char*)&Bs[cur][0]
                    + row * 128 + ((ks * 64 + g * 16) ^ ((row & 7) << 4)));
            }
            #pragma unroll
            for (int mi = 0; mi < MR; ++mi)
                #pragma unroll
                for (int ni = 0; ni < NR; ++ni)
                    acc[mi][ni] = __builtin_amdgcn_mfma_f32_16x16x32_bf16(
                        af[mi], bfr[ni], acc[mi][ni], 0, 0, 0);
        }
        __syncthreads();
    }

    float bv[NR];
    #pragma unroll
    for (int ni = 0; ni < NR; ++ni)
        bv[ni] = bias[n0 + wc * WC + ni * 16 + c];

    #pragma unroll
    for (int mi = 0; mi < MR; ++mi) {
        #pragma unroll
        for (int j = 0; j < 4; ++j) {
            const int row = m0 + wr * WR + mi * 16 + g * 4 + j;
            #pragma unroll
            for (int ni = 0; ni < NR; ++ni) {
                float v = acc[mi][ni][j] + bv[ni];
                if (ACT) v = fmaxf(v, 0.f);
                const int col = n0 + wc * WC + ni * 16 + c;
                if (OBF) Cb[(size_t)row * N + col] = f2bf(v);
                else     Cf[(size_t)row * N + col] = v;
            }
        }
    }
}

// ---------------------------------------------------------------------------
// Fused full-row GEMM + residual + LayerNorm (two-pass variance), 2-phase
// double-buffered.  BM=16 x N=256, 256 blocks x 256 threads. (r10 verified)
// ---------------------------------------------------------------------------
template<int K>
__global__ __launch_bounds__(256)
void rowgemm_ln(const ushort* __restrict__ A, const ushort* __restrict__ WT,
                const float* __restrict__ bias, const float* __restrict__ lg,
                const float* __restrict__ lb, float* __restrict__ x,
                ushort* __restrict__ xb)
{
    constexpr int BK = 64, N = 256;
    __shared__ __align__(16) ushort As[2][16 * BK];
    __shared__ __align__(16) ushort Bs[2][N * BK];
    __shared__ float rsum[4][16], rsq[4][16], mval[16], ival[16];

    const int tid = threadIdx.x;
    const int m0 = blockIdx.x * 16;
    const int wid = tid >> 6, lane = tid & 63;
    const int g = lane >> 4, c = lane & 15;

    auto stage = [&](int buf, int k0) {
        if (tid < 128) {   // A: 2KB
            const int o = tid * 16;
            const int r = o >> 7;
            const int cb = (o & 127) ^ ((r & 7) << 4);
            async_ld16(A + (size_t)(m0 + r) * K + k0 + (cb >> 1),
                       (char*)&As[buf][0] + o);
        }
        #pragma unroll
        for (int it = 0; it < 8; ++it) {   // B: 32KB
            const int o = tid * 16 + it * 4096;
            const int r = o >> 7;
            const int cb = (o & 127) ^ ((r & 7) << 4);
            async_ld16(WT + (size_t)r * K + k0 + (cb >> 1),
                       (char*)&Bs[buf][0] + o);
        }
    };

    f32x4 acc[4] = {};

    stage(0, 0);
    __syncthreads();

    int cur = 0;
    for (int k0 = 0; k0 < K; k0 += BK, cur ^= 1) {
        if (k0 + BK < K) stage(cur ^ 1, k0 + BK);

        #pragma unroll
        for (int ks = 0; ks < 2; ++ks) {
            const bf16x8 af = *(const bf16x8*)((const char*)&As[cur][0]
                + c * 128 + ((ks * 64 + g * 16) ^ ((c & 7) << 4)));
            #pragma unroll
            for (int ni = 0; ni < 4; ++ni) {
                const int row = wid * 64 + ni * 16 + c;
                const bf16x8 bf = *(const bf16x8*)((const char*)&Bs[cur][0]
                    + row * 128 + ((ks * 64 + g * 16) ^ ((row & 7) << 4)));
                acc[ni] = __builtin_amdgcn_mfma_f32_16x16x32_bf16(af, bf, acc[ni], 0, 0, 0);
            }
        }
        __syncthreads();
    }

    float bv[4], glv[4], blv[4];
    #pragma unroll
    for (int ni = 0; ni < 4; ++ni) {
        const int col = wid * 64 + ni * 16 + c;
        bv[ni] = bias[col]; glv[ni] = lg[col]; blv[ni] = lb[col];
    }

    // pass 1: v = acc + bias + residual; row sums -> mean
    #pragma unroll
    for (int j = 0; j < 4; ++j) {
        const int row = g * 4 + j;
        float s = 0.f;
        #pragma unroll
        for (int ni = 0; ni < 4; ++ni) {
            const int col = wid * 64 + ni * 16 + c;
            float vv = acc[ni][j] + bv[ni] + x[(size_t)(m0 + row) * N + col];
            acc[ni][j] = vv;
            s += vv;
        }
        #pragma unroll
        for (int off = 1; off < 16; off <<= 1) s += __shfl_xor(s, off);
        if (c == 0) rsum[wid][row] = s;
    }
    __syncthreads();
    if (tid < 16)
        mval[tid] = (rsum[0][tid] + rsum[1][tid] + rsum[2][tid] + rsum[3][tid])
                    * (1.f / N);
    __syncthreads();

    // pass 2: variance of deviations (matches reference arithmetic)
    #pragma unroll
    for (int j = 0; j < 4; ++j) {
        const int row = g * 4 + j;
        const float mean = mval[row];
        float q = 0.f;
        #pragma unroll
        for (int ni = 0; ni < 4; ++ni) {
            const float d = acc[ni][j] - mean;
            q += d * d;
        }
        #pragma unroll
        for (int off = 1; off < 16; off <<= 1) q += __shfl_xor(q, off);
        if (c == 0) rsq[wid][row] = q;
    }
    __syncthreads();
    if (tid < 16) {
        const float q = rsq[0][tid] + rsq[1][tid] + rsq[2][tid] + rsq[3][tid];
        ival[tid] = rsqrtf(q * (1.f / N) + LN_EPS);
    }
    __syncthreads();

    #pragma unroll
    for (int j = 0; j < 4; ++j) {
        const int row = g * 4 + j;
        const float mean = mval[row], inv = ival[row];
        #pragma unroll
        for (int ni = 0; ni < 4; ++ni) {
            const int col = wid * 64 + ni * 16 + c;
            const float y = (acc[ni][j] - mean) * inv * glv[ni] + blv[ni];
            x[(size_t)(m0 + row) * N + col] = y;
            xb[(size_t)(m0 + row) * N + col] = f2bf(y);
        }
    }
}

// ---------------------------------------------------------------------------
// Flash attention v6c: round-10 structure + XCD-chunked block swizzle so the
// 16 q-blocks sharing one (b,h)'s K/V land on ONE XCD (K/V L2-resident there;
// default round-robin duplicated them across all 8 XCD L2s).
// ---------------------------------------------------------------------------
__global__ __launch_bounds__(256)
void attn_mfma6(const ushort* __restrict__ qkv, const int* __restrict__ mask,
                ushort* __restrict__ out)
{
    const int tid = threadIdx.x;
    const int lane = tid & 63, wid = tid >> 6;
    const int g = lane >> 4, c = lane & 15;
    const int work = xcd_swz(blockIdx.x, 512);   // XCD k: bh 4k..4k+3
    const int qblk = work & 15;                // 16 q-blocks of 64
    const int bh = work >> 4;                  // 0..31
    const int h = bh & (NH - 1), b = bh >> 3;
    const int q0 = qblk * 64 + wid * 16;

    __shared__ __align__(16) ushort Kb[2][128 * 32];    // [key][32d] 64B rows, swz
    __shared__ __align__(16) ushort Vs[2][2][128][16];  // [dhalf][key][16d]
    __shared__ __align__(16) ushort Pl[4][16][136];     // per-wave [q][key], 272B rows
    __shared__ __align__(16) float  sbias[SS];
    __shared__ int mflag[4];

    const ushort* base  = qkv + (size_t)b * SS * 768;
    const ushort* kbase = base + DMODEL + h * HDIM;
    const ushort* vbase = base + 2 * DMODEL + h * HDIM;

    {   // mask bias + per-wave "any masked" flag
        const int i = tid * 4;
        const int4 mv = *reinterpret_cast<const int4*>(mask + b * SS + i);
        float4 bv;
        bv.x = mv.x ? 0.f : -3.4e38f;
        bv.y = mv.y ? 0.f : -3.4e38f;
        bv.z = mv.z ? 0.f : -3.4e38f;
        bv.w = mv.w ? 0.f : -3.4e38f;
        *reinterpret_cast<float4*>(&sbias[i]) = bv;
        const int miss = __any(!(mv.x && mv.y && mv.z && mv.w));
        if (lane == 0) mflag[wid] = miss;
    }

    const bf16x8 qfrag = *(const bf16x8*)(
        base + (size_t)(q0 + c) * 768 + h * HDIM + g * 8);

    // staging assignments (o16 = tid*16 byte offset; each async covers 4KB)
    const int o16  = tid * 16;
    const int krow = o16 >> 6;                              // key 0..63 (64B rows)
    const int kin  = (o16 & 63) ^ ((krow & 3) << 4);        // swizzled inner bytes
    const int vkey = o16 >> 5;                              // key 0..127 (32B rows)
    const int vd8  = ((o16 >> 4) & 1) << 3;                 // d sub-offset 0/8

    #define STAGE(buf, koff)                                                     \
        do {                                                                     \
            async_ld16(kbase + (size_t)((koff) + krow) * 768 + (kin >> 1),       \
                       (char*)&Kb[buf][0] + o16);                                \
            async_ld16(kbase + (size_t)((koff) + 64 + krow) * 768 + (kin >> 1),  \
                       (char*)&Kb[buf][0] + o16 + 4096);                         \
            async_ld16(vbase + (size_t)((koff) + vkey) * 768 + vd8,              \
                       (char*)&Vs[buf][0][0][0] + o16);                          \
            async_ld16(vbase + (size_t)((koff) + vkey) * 768 + 16 + vd8,         \
                       (char*)&Vs[buf][0][0][0] + o16 + 4096);                   \
        } while (0)

    STAGE(0, 0);
    __syncthreads();
    const int anyMasked = mflag[0] | mflag[1] | mflag[2] | mflag[3];

    float m = -1e30f, lpart = 0.f;
    f32x4 o0 = {0.f, 0.f, 0.f, 0.f}, o1 = {0.f, 0.f, 0.f, 0.f};
    const f32x4 zf = {0.f, 0.f, 0.f, 0.f};

    for (int t = 0; t < 8; ++t) {
        const int cur = t & 1;
        if (t < 7) STAGE(cur ^ 1, (t + 1) * 128);

        // ---- S^T tiles: rows = keys (4/lane), cols = q (=c)
        f32x4 s[8];
        __builtin_amdgcn_s_setprio(1);
        #pragma unroll
        for (int kt = 0; kt < 8; ++kt) {
            const int row = kt * 16 + c;
            const bf16x8 kf = *(const bf16x8*)((const char*)&Kb[cur][0]
                + row * 64 + ((g * 16) ^ ((c & 3) << 4)));
            s[kt] = __builtin_amdgcn_mfma_f32_16x16x32_bf16(kf, qfrag, zf, 0, 0, 0);
        }
        __builtin_amdgcn_s_setprio(0);

        if (anyMasked) {
            #pragma unroll
            for (int kt = 0; kt < 8; ++kt) {
                const f32x4 bv = *reinterpret_cast<const f32x4*>(
                    &sbias[t * 128 + kt * 16 + g * 4]);
                #pragma unroll
                for (int r = 0; r < 4; ++r) s[kt][r] += bv[r];
            }
        }

        // ---- online softmax, defer-rescale (per-lane partial max test)
        float mx = fmaxf(fmaxf(s[0][0], s[0][1]), fmaxf(s[0][2], s[0][3]));
        #pragma unroll
        for (int kt = 1; kt < 8; ++kt)
            mx = fmaxf(mx, fmaxf(fmaxf(s[kt][0], s[kt][1]),
                                 fmaxf(s[kt][2], s[kt][3])));
        if (!__all(mx <= m + 8.f)) {
            float fm = fmaxf(mx, __shfl_xor(mx, 16));
            fm = fmaxf(fm, __shfl_xor(fm, 32));
            const float mn = fmaxf(m, fm);
            const float sc = __expf(m - mn);
            m = mn;
            lpart *= sc;
            float scr[4];
            #pragma unroll
            for (int r = 0; r < 4; ++r) scr[r] = __shfl(sc, g * 4 + r);
            #pragma unroll
            for (int r = 0; r < 4; ++r) { o0[r] *= scr[r]; o1[r] *= scr[r]; }
        }

        float ls = 0.f;
        #pragma unroll
        for (int kt = 0; kt < 8; ++kt) {
            const float p0 = __expf(s[kt][0] - m);
            const float p1 = __expf(s[kt][1] - m);
            const float p2 = __expf(s[kt][2] - m);
            const float p3 = __expf(s[kt][3] - m);
            ls += (p0 + p1) + (p2 + p3);
            uint2 pk2 = make_uint2(pack2(p0, p1), pack2(p2, p3));
            *reinterpret_cast<uint2*>(&Pl[wid][c][kt * 16 + g * 4]) = pk2;
        }
        lpart += ls;

        // ---- PV: O[16q][32d] += P[16q][128k] @ V[128k][32d]
        __builtin_amdgcn_s_setprio(1);
        #pragma unroll
        for (int ks = 0; ks < 4; ++ks) {
            const int vr0 = ks * 32 + g * 8;
            union UU { s16x4 h[2]; bf16x8 v; } u0, u1;
            u0.h[0] = tr16(&Vs[cur][0][vr0][c]);
            u0.h[1] = tr16(&Vs[cur][0][vr0 + 4][c]);
            u1.h[0] = tr16(&Vs[cur][1][vr0][c]);
            u1.h[1] = tr16(&Vs[cur][1][vr0 + 4][c]);
            tr_fence();
            const bf16x8 pa = *(const bf16x8*)&Pl[wid][c][ks * 32 + g * 8];
            o0 = __builtin_amdgcn_mfma_f32_16x16x32_bf16(pa, u0.v, o0, 0, 0, 0);
            o1 = __builtin_amdgcn_mfma_f32_16x16x32_bf16(pa, u1.v, o1, 0, 0, 0);
        }
        __builtin_amdgcn_s_setprio(0);
        __syncthreads();
    }
    #undef STAGE

    // ---- finalize: reduce per-lane lsum partials, normalize, store
    float lsum = lpart;
    lsum += __shfl_xor(lsum, 16);
    lsum += __shfl_xor(lsum, 32);
    const float rs = 1.f / lsum;
    float inv[4];
    #pragma unroll
    for (int r = 0; r < 4; ++r) inv[r] = __shfl(rs, g * 4 + r);
    #pragma unroll
    for (int r = 0; r < 4; ++r) {
        ushort* op = out + (size_t)(b * SS + q0 + g * 4 + r) * DMODEL + h * HDIM;
        op[c]      = f2bf(o0[r] * inv[r]);
        op[16 + c] = f2bf(o1[r] * inv[r]);
    }
}

// ---------------------------------------------------------------------------
extern "C" void kernel_launch(void* const* d_in, const int* in_sizes, int n_in,
                              void* d_out, int out_size, void* d_ws, size_t ws_size,
                              hipStream_t stream)
{
    const float* x_in   = (const float*)d_in[0];
    const int*   maskp  = (const int*)d_in[1];
    const float* qkv_w  = (const float*)d_in[2];
    const float* qkv_b  = (const float*)d_in[3];
    const float* fc_w   = (const float*)d_in[4];
    const float* fc_b   = (const float*)d_in[5];
    const float* ln1_g  = (const float*)d_in[6];
    const float* ln1_b  = (const float*)d_in[7];
    const float* ln2_g  = (const float*)d_in[8];
    const float* ln2_b  = (const float*)d_in[9];
    const float* ff1_w  = (const float*)d_in[10];
    const float* ff1_b  = (const float*)d_in[11];
    const float* ff2_w  = (const float*)d_in[12];
    const float* ff2_b  = (const float*)d_in[13];

    float* x = (float*)d_out;                       // [4096,256] fp32 residual

    ushort* wt_qkv = (ushort*)d_ws;                 // [L][768][256]
    ushort* wt_fc  = wt_qkv + (size_t)NL * 768 * 256;
    ushort* wt_ff1 = wt_fc  + (size_t)NL * 256 * 256;
    ushort* wt_ff2 = wt_ff1 + (size_t)NL * 1024 * 256;
    ushort* big    = wt_ff2 + (size_t)NL * 256 * 1024;  // qkv_bf / h_bf (8MB)
    ushort* attn_bf= big + (size_t)MROWS * FFDIM;
    ushort* x_bf   = attn_bf + (size_t)MROWS * DMODEL;

    wconv_all<<<dim3(768, 1, NL), 256, 0, stream>>>(
        qkv_w, fc_w, ff1_w, ff2_w, wt_qkv, wt_fc, wt_ff1, wt_ff2);
    convert_x<<<dim3(MROWS * DMODEL / 1024), 256, 0, stream>>>(x_in, x, x_bf);

    for (int l = 0; l < NL; ++l) {
        // qkv (bf16 out) [4096,768]
        gemm_mfma<64, 128, 2, 2, 0, 1><<<dim3(6, 64), 256, 0, stream>>>(
            x_bf, wt_qkv + (size_t)l * 768 * 256, qkv_b + l * 768,
            nullptr, big, 768, 256);
        // attention -> attn_bf [4096,256] bf16
        attn_mfma6<<<dim3(512), 256, 0, stream>>>(big, maskp, attn_bf);
        // x = LN1(attn @ fc_w + b + x)
        rowgemm_ln<256><<<dim3(256), 256, 0, stream>>>(
            attn_bf, wt_fc + (size_t)l * 256 * 256, fc_b + l * 256,
            ln1_g + l * DMODEL, ln1_b + l * DMODEL, x, x_bf);
        // h = relu(x @ ff1_w + b) (bf16 out) [4096,1024]
        gemm_mfma<128, 128, 2, 2, 1, 1><<<dim3(8, 32), 256, 0, stream>>>(
            x_bf, wt_ff1 + (size_t)l * 1024 * 256, ff1_b + l * FFDIM,
            nullptr, big, 1024, 256);
        // x = LN2(h @ ff2_w + b + x)
        rowgemm_ln<1024><<<dim3(256), 256, 0, stream>>>(
            big, wt_ff2 + (size_t)l * 256 * 1024, ff2_b + l * DMODEL,
            ln2_g + l * DMODEL, ln2_b + l * DMODEL, x, x_bf);
    }
}